// Round 7
// baseline (3170.671 us; speedup 1.0000x reference)
//
#include <hip/hip_runtime.h>
#include <math.h>

// Problem constants (match reference file)
#define NNODES 100000
#define NEDGE  1600000
#define HD     64
#define INDIM  256

#define RB   32                 // rows per bucket
#define RBH  16                 // rows per half-bucket (stage kernels)
#define NB   3125               // NNODES / RB (exact)
#define NKEY (4 * NB)           // 12500 (a, bucket) regions
#define CAP  1024               // pack LDS capacity
#define CAPH 512                // per-adjacency stage slot per half-bucket (mean 256, +16 sigma)
#define CHK  64                 // chunks per adjacency (deterministic scatter)
#define EPC  (NEDGE / CHK)      // 25000 edges per chunk
#define NCH  100                // node chunks (type sort)
#define NPC  (NNODES / NCH)     // 1000 nodes per chunk

static constexpr size_t NP = (size_t)NNODES * HD;   // 6.4M elems per [N,H] plane
static constexpr size_t ME = (size_t)4 * NEDGE;     // 6.4M edges total
static constexpr int    M2 = NKEY * CHK;            // 800000 (key,chunk) counters
static constexpr int    SCAN1B = (M2 + 1023) / 1024;  // 782

// workspace layout (floats) — total ~200.5 MB
static constexpr size_t XPB_OFF   = 0;                   // uint bf16x2 (x0,x1): NP
static constexpr size_t SPB_OFF   = NP;                  // ushort s1 plane: NP/2 floats; ushort t1 plane: NP/2 floats
static constexpr size_t CRES_OFF  = 2 * NP;              // s2 accumulator (f32)
static constexpr size_t CZ0_OFF   = 3 * NP;              // z0 (f32)
static constexpr size_t CZ1_OFF   = 4 * NP;              // z1 (f32)
static constexpr size_t S2B_OFF   = 5 * NP;              // ushort bf16 s2: NP/2 floats
static constexpr size_t EPK_OFF   = 5 * NP + NP / 2;     // int2 (lr|col,val): 2*ME
static constexpr size_t CNT2_OFF  = EPK_OFF + 2 * ME;    // M2 ints [key][chunk]
static constexpr size_t OFF2_OFF  = CNT2_OFF + M2;       // M2 ints
static constexpr size_t PART_OFF  = OFF2_OFF + M2;       // 1024 ints
static constexpr size_t ROFF_OFF  = PART_OFF + 1024;     // NKEY*RB ints
static constexpr size_t NCNT_OFF  = ROFF_OFF + (size_t)NKEY * RB;  // 512 ints
static constexpr size_t NOFF_OFF  = NCNT_OFF + 512;      // 512 ints
static constexpr size_t NPERM_OFF = NOFF_OFF + 512;      // NNODES ints

// ---------------- helpers ----------------
__device__ __forceinline__ float wave_bsum(float v) {
#pragma unroll
  for (int m = 1; m < 64; m <<= 1) v += __shfl_xor(v, m, 64);
  return v;
}

__device__ __forceinline__ unsigned int bf2pack(float a, float b) {
  unsigned int ua = __float_as_uint(a);
  ua += 0x7FFFu + ((ua >> 16) & 1u);        // RNE
  unsigned int ub = __float_as_uint(b);
  ub += 0x7FFFu + ((ub >> 16) & 1u);
  return (ua >> 16) | (ub & 0xFFFF0000u);
}
__device__ __forceinline__ unsigned short bf1(float a) {
  unsigned int ua = __float_as_uint(a);
  ua += 0x7FFFu + ((ua >> 16) & 1u);
  return (unsigned short)(ua >> 16);
}
__device__ __forceinline__ float bf_lo(unsigned int g) { return __uint_as_float(g << 16); }
__device__ __forceinline__ float bf_hi(unsigned int g) { return __uint_as_float(g & 0xFFFF0000u); }
__device__ __forceinline__ float bf_s(unsigned short g) {
  return __uint_as_float((unsigned int)g << 16);
}
// force a uniform float load into an SGPR (keeps weight tables out of the VGPR budget)
__device__ __forceinline__ float sload(const float* p) {
  return __uint_as_float(__builtin_amdgcn_readfirstlane(__float_as_uint(*p)));
}
// softmax coefficient helpers (identical math to the old wcoef kernel)
__device__ __forceinline__ void sm3d(float a0, float a1, float a2, float sc, float* o) {
  float m = fmaxf(a0, fmaxf(a1, a2));
  float e0 = expf(a0 - m), e1 = expf(a1 - m), e2 = expf(a2 - m);
  float inv = sc / (e0 + e1 + e2);
  o[0] = e0 * inv; o[1] = e1 * inv; o[2] = e2 * inv;
}
__device__ __forceinline__ void sm2d(float a0, float a1, float sc, float* o) {
  float m = fmaxf(a0, a1);
  float e0 = expf(a0 - m), e1 = expf(a1 - m);
  float inv = sc / (e0 + e1);
  o[0] = e0 * inv; o[1] = e1 * inv;
}
__device__ __forceinline__ void sm4d(float a0, float a1, float a2, float a3, float sc, float* o) {
  float m = fmaxf(fmaxf(a0, a1), fmaxf(a2, a3));
  float e0 = expf(a0 - m), e1 = expf(a1 - m), e2 = expf(a2 - m), e3 = expf(a3 - m);
  float inv = sc / (e0 + e1 + e2 + e3);
  o[0] = e0 * inv; o[1] = e1 * inv; o[2] = e2 * inv; o[3] = e3 * inv;
}

// ================= node type sort (deterministic, chunked) =================
__global__ __launch_bounds__(256) void nhist_kernel(const int* __restrict__ types,
                                                    int* __restrict__ ncnt) {
  __shared__ int c[4];
  int ch = blockIdx.x;
  if (threadIdx.x < 4) c[threadIdx.x] = 0;
  __syncthreads();
  int base = ch * NPC;
  for (int i = base + threadIdx.x; i < base + NPC; i += 256)
    atomicAdd(&c[types[i]], 1);
  __syncthreads();
  if (threadIdx.x < 4) ncnt[threadIdx.x * NCH + ch] = c[threadIdx.x];
}

__global__ __launch_bounds__(256) void nscan_kernel(const int* __restrict__ ncnt,
                                                    int* __restrict__ noff) {
  __shared__ int sdata[256];
  int t = threadIdx.x;
  int i0 = t * 2;
  int v0 = (i0 < 4 * NCH) ? ncnt[i0] : 0;
  int v1 = (i0 + 1 < 4 * NCH) ? ncnt[i0 + 1] : 0;
  int ts = v0 + v1;
  sdata[t] = ts;
  __syncthreads();
  for (int o = 1; o < 256; o <<= 1) {
    int x = (t >= o) ? sdata[t - o] : 0;
    __syncthreads();
    sdata[t] += x;
    __syncthreads();
  }
  int excl = sdata[t] - ts;
  if (i0 < 4 * NCH) noff[i0] = excl;
  if (i0 + 1 < 4 * NCH) noff[i0 + 1] = excl + v0;
}

__global__ __launch_bounds__(256) void nscatter_kernel(const int* __restrict__ types,
                                                       const int* __restrict__ noff,
                                                       int* __restrict__ nperm) {
  __shared__ int cur[4];
  int ch = blockIdx.x;
  if (threadIdx.x < 4) cur[threadIdx.x] = noff[threadIdx.x * NCH + ch];
  __syncthreads();
  int base = ch * NPC;
  for (int i = base + threadIdx.x; i < base + NPC; i += 256) {
    int pos = atomicAdd(&cur[types[i]], 1);
    nperm[pos] = i;
  }
}

// ---------------- typed projection + both affines, type-sorted, 8 nodes/wave ----------------
__global__ __launch_bounds__(256) void hid2_kernel(
    const float* __restrict__ feats, const int* __restrict__ types,
    const int* __restrict__ nperm,
    const float* __restrict__ type_W, const float* __restrict__ type_b,
    const float* __restrict__ W0, const float* __restrict__ b0,
    const float* __restrict__ W1, const float* __restrict__ b1,
    unsigned int* __restrict__ xpb) {
  __shared__ float sh_h[4][8][64];
  int t = threadIdx.x, wv = t >> 6, lane = t & 63;
  int idx0 = blockIdx.x * 32 + wv * 8;
  int nj[8];
#pragma unroll
  for (int j = 0; j < 8; j++)
    nj[j] = __builtin_amdgcn_readfirstlane(nperm[idx0 + j]);
  int t0 = __builtin_amdgcn_readfirstlane(types[nj[0]]);
  int t7 = __builtin_amdgcn_readfirstlane(types[nj[7]]);
  float acc[8];
  if (t0 == t7) {
    const float* W = type_W + (size_t)t0 * (INDIM * HD);
    float bias = type_b[t0 * HD + lane];
#pragma unroll
    for (int j = 0; j < 8; j++) acc[j] = bias;
    for (int k = 0; k < INDIM; k += 4) {
#pragma unroll
      for (int kk = 0; kk < 4; kk++) {
        float wk = W[(k + kk) * HD + lane];
#pragma unroll
        for (int j = 0; j < 8; j++)
          acc[j] = fmaf(feats[(size_t)nj[j] * INDIM + k + kk], wk, acc[j]);
      }
    }
  } else {
    for (int j = 0; j < 8; j++) {
      int tj = __builtin_amdgcn_readfirstlane(types[nj[j]]);
      const float* W = type_W + (size_t)tj * (INDIM * HD);
      float a = type_b[tj * HD + lane];
      for (int k = 0; k < INDIM; k++)
        a = fmaf(feats[(size_t)nj[j] * INDIM + k], W[k * HD + lane], a);
      acc[j] = a;
    }
  }
#pragma unroll
  for (int j = 0; j < 8; j++) sh_h[wv][j][lane] = acc[j];
  float a0[8], a1[8];
  float bb0 = b0[lane], bb1 = b1[lane];
#pragma unroll
  for (int j = 0; j < 8; j++) { a0[j] = bb0; a1[j] = bb1; }
  for (int j2 = 0; j2 < 64; j2++) {
    float w0 = W0[j2 * HD + lane], w1 = W1[j2 * HD + lane];
#pragma unroll
    for (int j = 0; j < 8; j++) {
      float hv = sh_h[wv][j][j2];
      a0[j] = fmaf(hv, w0, a0[j]);
      a1[j] = fmaf(hv, w1, a1[j]);
    }
  }
#pragma unroll
  for (int j = 0; j < 8; j++)
    xpb[(size_t)nj[j] * HD + lane] = bf2pack(a0[j], a1[j]);
}

// ================= deterministic two-pass edge build (no global atomics) =================
__global__ __launch_bounds__(256) void histb2_kernel(const int* __restrict__ rows,
                                                     int* __restrict__ cnt2) {
  __shared__ int h[NB];
  int a = blockIdx.y, ch = blockIdx.x;
  for (int i = threadIdx.x; i < NB; i += 256) h[i] = 0;
  __syncthreads();
  int base = ch * EPC;
  for (int e = base + threadIdx.x; e < base + EPC; e += 256)
    atomicAdd(&h[rows[(size_t)a * NEDGE + e] >> 5], 1);
  __syncthreads();
  for (int b = threadIdx.x; b < NB; b += 256)
    cnt2[((size_t)(a * NB + b) << 6) | ch] = h[b];
}

__global__ __launch_bounds__(256) void scan1_kernel(const int* __restrict__ cnt2,
                                                    int* __restrict__ off2,
                                                    int* __restrict__ part) {
  __shared__ int sdata[256];
  int t = threadIdx.x;
  int base = blockIdx.x * 1024 + t * 4;
  int v0 = (base + 0 < M2) ? cnt2[base + 0] : 0;
  int v1 = (base + 1 < M2) ? cnt2[base + 1] : 0;
  int v2 = (base + 2 < M2) ? cnt2[base + 2] : 0;
  int v3 = (base + 3 < M2) ? cnt2[base + 3] : 0;
  int tsum = v0 + v1 + v2 + v3;
  sdata[t] = tsum;
  __syncthreads();
  for (int o = 1; o < 256; o <<= 1) {
    int x = (t >= o) ? sdata[t - o] : 0;
    __syncthreads();
    sdata[t] += x;
    __syncthreads();
  }
  int excl = sdata[t] - tsum;
  if (t == 255) part[blockIdx.x] = sdata[255];
  if (base + 0 < M2) off2[base + 0] = excl;
  if (base + 1 < M2) off2[base + 1] = excl + v0;
  if (base + 2 < M2) off2[base + 2] = excl + v0 + v1;
  if (base + 3 < M2) off2[base + 3] = excl + v0 + v1 + v2;
}

__global__ __launch_bounds__(1024) void scan2_kernel(int* __restrict__ part) {
  __shared__ int sdata[1024];
  int t = threadIdx.x;
  int v = (t < SCAN1B) ? part[t] : 0;
  sdata[t] = v;
  __syncthreads();
  for (int o = 1; o < 1024; o <<= 1) {
    int x = (t >= o) ? sdata[t - o] : 0;
    __syncthreads();
    sdata[t] += x;
    __syncthreads();
  }
  if (t < SCAN1B) part[t] = sdata[t] - v;  // exclusive
}

__global__ __launch_bounds__(256) void scan3_kernel(int* __restrict__ off2,
                                                    const int* __restrict__ part) {
  int p = part[blockIdx.x];
  int t = threadIdx.x;
#pragma unroll
  for (int j = 0; j < 4; j++) {
    int i = blockIdx.x * 1024 + j * 256 + t;
    if (i < M2) off2[i] += p;
  }
}

// pass 2: deterministic scatter of packed (lr|col,val) using LDS cursors
__global__ __launch_bounds__(256) void scatterd_kernel(
    const int* __restrict__ rows, const int* __restrict__ cols, const float* __restrict__ vals,
    const int* __restrict__ off2, int2* __restrict__ epk) {
  __shared__ int cur[NB];
  int a = blockIdx.y, ch = blockIdx.x;
  for (int b = threadIdx.x; b < NB; b += 256)
    cur[b] = off2[((size_t)(a * NB + b) << 6) | ch];
  __syncthreads();
  int base = ch * EPC;
  for (int e = base + threadIdx.x; e < base + EPC; e += 256) {
    size_t idx = (size_t)a * NEDGE + e;
    int r = rows[idx];
    int pos = atomicAdd(&cur[r >> 5], 1);
    epk[pos] = make_int2(((r & 31) << 17) | cols[idx], __float_as_int(vals[idx]));
  }
}

// pack: per bucket, coalesced read epk region, counting-sort by local row in LDS,
// write back sorted + rofftab  (key offsets computed from off2 directly)
__global__ __launch_bounds__(256) void pack_kernel(
    const int* __restrict__ off2,
    int2* __restrict__ epk, int* __restrict__ rofftab) {
  __shared__ int smeta[CAP];
  __shared__ float sval[CAP];
  __shared__ int h[RB], hc[RB];
  int key = blockIdx.x;
  int base = off2[(size_t)key << 6];
  int kend = (key + 1 < NKEY) ? off2[(size_t)(key + 1) << 6] : (int)ME;
  int n = kend - base;
  int t = threadIdx.x, wv = t >> 6, lane = t & 63;
  if (t < RB) h[t] = 0;
  __syncthreads();
  if (n <= CAP) {
    int lm[4]; float lv[4];
    int cl = 0;
#pragma unroll
    for (int j = 0; j < 4; j++) {
      int i = t + j * 256;
      if (i < n) {
        int2 p = epk[base + i];
        lm[cl] = p.x;
        lv[cl] = __int_as_float(p.y);
        cl++;
        atomicAdd(&h[p.x >> 17], 1);
      }
    }
    __syncthreads();
    if (wv == 0) {
      int v = (lane < RB) ? h[lane] : 0;
      int incl = v;
#pragma unroll
      for (int o = 1; o < RB; o <<= 1) {
        int x = __shfl_up(incl, o, 64);
        if (lane >= o) incl += x;
      }
      if (lane < RB) {
        int excl = incl - v;
        hc[lane] = excl;
        rofftab[(size_t)key * RB + lane] = excl;
      }
    }
    __syncthreads();
    for (int j = 0; j < cl; j++) {
      int p = atomicAdd(&hc[lm[j] >> 17], 1);
      smeta[p] = lm[j];
      sval[p] = lv[j];
    }
    __syncthreads();
    for (int i = t; i < n; i += 256)
      epk[base + i] = make_int2(smeta[i], __float_as_int(sval[i]));
  }
  // n > CAP: leave unsorted; stages use slow scan path (never expected)
}

// ================= SpMM stages: half-bucket blocks, 4 rows/wave, joint-pair gathers =====

// region lookup from off2 (keyoff kernel inlined)
__device__ __forceinline__ int key_base(const int* off2, int key) {
  return __builtin_amdgcn_readfirstlane(off2[(size_t)key << 6]);
}
__device__ __forceinline__ int key_end(const int* off2, int key) {
  return (key + 1 < NKEY)
             ? __builtin_amdgcn_readfirstlane(off2[(size_t)(key + 1) << 6])
             : (int)ME;
}

// stage 1: gather xpb (bf16 x0,x1); write spb_s/spb_t (split bf16 planes), cres, cz0, cz1
__global__ __launch_bounds__(256, 8) void st1_kernel(
    const int* __restrict__ off2,
    const int* __restrict__ rofftab, const int2* __restrict__ epk,
    const unsigned int* __restrict__ xpb,
    const float* __restrict__ as_seq0, const float* __restrict__ as_res0,
    const float* __restrict__ as_last_res0, const float* __restrict__ as_seq1,
    const float* __restrict__ as_last_res1,
    unsigned short* __restrict__ spb_s, unsigned short* __restrict__ spb_t,
    float* __restrict__ cres, float* __restrict__ cz0, float* __restrict__ cz1) {
  __shared__ int2 se[4 * CAPH];     // .x = byte offset (col<<8), .y = val bits
  __shared__ int ro[4][RBH + 1];
  int bb = blockIdx.x;
  int b = bb >> 1, bh = bb & 1;
  int t = threadIdx.x, wv = t >> 6, lane = t & 63;
  // arch weights (wcoef inlined, identical math)
  float w_s1[4], w_res[4], w_z0[4], w_t1[4], w_z1[4], tmp[4];
  sm3d(sload(as_seq0 + 0), sload(as_seq0 + 1), sload(as_seq0 + 2), 1.f / 3.f, tmp);
  w_s1[0] = tmp[0]; w_s1[1] = tmp[1]; w_s1[2] = tmp[2]; w_s1[3] = 0.f;
  sm4d(sload(as_res0 + 0), sload(as_res0 + 1), sload(as_res0 + 2), sload(as_res0 + 3),
       0.25f, w_res);
  sm3d(sload(as_last_res0 + 0), sload(as_last_res0 + 1), sload(as_last_res0 + 2),
       1.f / 3.f, tmp);
  w_z0[0] = tmp[0]; w_z0[1] = tmp[1]; w_z0[2] = 0.f; w_z0[3] = tmp[2];
  sm3d(sload(as_seq1 + 0), sload(as_seq1 + 1), sload(as_seq1 + 2), 1.f / 3.f, tmp);
  w_t1[0] = tmp[0]; w_t1[1] = tmp[1]; w_t1[2] = tmp[2]; w_t1[3] = 0.f;
  sm3d(sload(as_last_res1 + 0), sload(as_last_res1 + 1), sload(as_last_res1 + 2),
       1.f / 3.f, tmp);
  w_z1[0] = tmp[0]; w_z1[1] = tmp[1]; w_z1[2] = 0.f; w_z1[3] = tmp[2];

  int nA[4], baseA[4];
  bool fits = true;
#pragma unroll
  for (int a = 0; a < 4; a++) {
    int key = a * NB + b;
    int base = key_base(off2, key);
    int ntot = key_end(off2, key) - base;
    int rs, re;
    if (ntot <= CAP) {
      int mid = __builtin_amdgcn_readfirstlane(rofftab[(size_t)key * RB + RBH]);
      rs = bh ? mid : 0;
      re = bh ? ntot : mid;
    } else {  // pack left region unsorted: both halves slow-scan the whole region
      rs = 0; re = ntot; fits = false;
    }
    baseA[a] = base + rs;
    nA[a] = re - rs;
    if (nA[a] > CAPH) fits = false;
  }
  int rowbase = b * RB + bh * RBH + wv * 4;
  if (fits) {
#pragma unroll
    for (int a = 0; a < 4; a++) {
      int n = nA[a], base = baseA[a];
      for (int i = t; i < n; i += 256) {
        int2 p = epk[base + i];
        se[a * CAPH + i] = make_int2((p.x & 0x1FFFF) << 8, p.y);
      }
    }
    if (t < 4 * (RBH + 1)) {
      int a = t / (RBH + 1), rr = t % (RBH + 1);
      int key = a * NB + b;
      int kb = off2[(size_t)key << 6];
      int ke = (key + 1 < NKEY) ? off2[(size_t)(key + 1) << 6] : (int)ME;
      int rs0 = bh ? rofftab[(size_t)key * RB + RBH] : 0;
      int ar = bh * RBH + rr;
      int v = (ar < RB) ? rofftab[(size_t)key * RB + ar] : (ke - kb);
      ro[a][rr] = v - rs0;
    }
    __syncthreads();
    const unsigned char* xb = (const unsigned char*)xpb;
    unsigned lane4 = (unsigned)lane << 2;
    // finish a segment 4-deep + scalar tail, both bf16 halves
    auto tl2 = [&](const int2* sp, int i, int e, float& s0, float& s1,
                   float& t0, float& t1) {
      for (; i + 3 < e; i += 4) {
        int2 p0 = sp[i], p1 = sp[i + 1], p2 = sp[i + 2], p3 = sp[i + 3];
        unsigned g0 = *(const unsigned int*)(xb + ((unsigned)p0.x + lane4));
        unsigned g1 = *(const unsigned int*)(xb + ((unsigned)p1.x + lane4));
        unsigned g2 = *(const unsigned int*)(xb + ((unsigned)p2.x + lane4));
        unsigned g3 = *(const unsigned int*)(xb + ((unsigned)p3.x + lane4));
        float v0 = __int_as_float(p0.y), v1 = __int_as_float(p1.y);
        float v2 = __int_as_float(p2.y), v3 = __int_as_float(p3.y);
        s0 = fmaf(v0, bf_lo(g0), s0); t0 = fmaf(v0, bf_hi(g0), t0);
        s1 = fmaf(v1, bf_lo(g1), s1); t1 = fmaf(v1, bf_hi(g1), t1);
        s0 = fmaf(v2, bf_lo(g2), s0); t0 = fmaf(v2, bf_hi(g2), t0);
        s1 = fmaf(v3, bf_lo(g3), s1); t1 = fmaf(v3, bf_hi(g3), t1);
      }
      for (; i < e; i++) {
        int2 p = sp[i];
        unsigned g = *(const unsigned int*)(xb + ((unsigned)p.x + lane4));
        float v = __int_as_float(p.y);
        s0 = fmaf(v, bf_lo(g), s0); t0 = fmaf(v, bf_hi(g), t0);
      }
    };
    for (int r8 = 0; r8 < 4; r8++) {
      int r = wv * 4 + r8;
      float vs1 = 0.f, vt1 = 0.f, vres = 0.f, vz0 = 0.f, vz1 = 0.f;
#pragma unroll
      for (int ap = 0; ap < 2; ap++) {
        int aA = ap << 1, aB = aA | 1;
        const int2* spA = se + aA * CAPH;
        const int2* spB = se + aB * CAPH;
        int iA = ro[aA][r], eA = ro[aA][r + 1];
        int iB = ro[aB][r], eB = ro[aB][r + 1];
        float sA0 = 0.f, sA1 = 0.f, tA0 = 0.f, tA1 = 0.f;
        float sB0 = 0.f, sB1 = 0.f, tB0 = 0.f, tB1 = 0.f;
        int dA = eA - iA, dB = eB - iB;
        int m = (dA < dB ? dA : dB) >> 2;   // joint 4+4: 8 gathers in flight
        for (int k = 0; k < m; k++) {
          int2 a0 = spA[iA], a1 = spA[iA + 1], a2 = spA[iA + 2], a3 = spA[iA + 3];
          int2 b0 = spB[iB], b1 = spB[iB + 1], b2 = spB[iB + 2], b3 = spB[iB + 3];
          unsigned gA0 = *(const unsigned int*)(xb + ((unsigned)a0.x + lane4));
          unsigned gA1 = *(const unsigned int*)(xb + ((unsigned)a1.x + lane4));
          unsigned gA2 = *(const unsigned int*)(xb + ((unsigned)a2.x + lane4));
          unsigned gA3 = *(const unsigned int*)(xb + ((unsigned)a3.x + lane4));
          unsigned gB0 = *(const unsigned int*)(xb + ((unsigned)b0.x + lane4));
          unsigned gB1 = *(const unsigned int*)(xb + ((unsigned)b1.x + lane4));
          unsigned gB2 = *(const unsigned int*)(xb + ((unsigned)b2.x + lane4));
          unsigned gB3 = *(const unsigned int*)(xb + ((unsigned)b3.x + lane4));
          float vA0 = __int_as_float(a0.y), vA1 = __int_as_float(a1.y);
          float vA2 = __int_as_float(a2.y), vA3 = __int_as_float(a3.y);
          float vB0 = __int_as_float(b0.y), vB1 = __int_as_float(b1.y);
          float vB2 = __int_as_float(b2.y), vB3 = __int_as_float(b3.y);
          sA0 = fmaf(vA0, bf_lo(gA0), sA0); tA0 = fmaf(vA0, bf_hi(gA0), tA0);
          sA1 = fmaf(vA1, bf_lo(gA1), sA1); tA1 = fmaf(vA1, bf_hi(gA1), tA1);
          sA0 = fmaf(vA2, bf_lo(gA2), sA0); tA0 = fmaf(vA2, bf_hi(gA2), tA0);
          sA1 = fmaf(vA3, bf_lo(gA3), sA1); tA1 = fmaf(vA3, bf_hi(gA3), tA1);
          sB0 = fmaf(vB0, bf_lo(gB0), sB0); tB0 = fmaf(vB0, bf_hi(gB0), tB0);
          sB1 = fmaf(vB1, bf_lo(gB1), sB1); tB1 = fmaf(vB1, bf_hi(gB1), tB1);
          sB0 = fmaf(vB2, bf_lo(gB2), sB0); tB0 = fmaf(vB2, bf_hi(gB2), tB0);
          sB1 = fmaf(vB3, bf_lo(gB3), sB1); tB1 = fmaf(vB3, bf_hi(gB3), tB1);
          iA += 4; iB += 4;
        }
        tl2(spA, iA, eA, sA0, sA1, tA0, tA1);
        tl2(spB, iB, eB, sB0, sB1, tB0, tB1);
        float sA = sA0 + sA1, tA = tA0 + tA1;
        float sB = sB0 + sB1, tB = tB0 + tB1;
        vs1  = fmaf(w_s1[aA], sA, fmaf(w_s1[aB], sB, vs1));
        vres = fmaf(w_res[aA], sA, fmaf(w_res[aB], sB, vres));
        vz0  = fmaf(w_z0[aA], sA, fmaf(w_z0[aB], sB, vz0));
        vt1  = fmaf(w_t1[aA], tA, fmaf(w_t1[aB], tB, vt1));
        vz1  = fmaf(w_z1[aA], tA, fmaf(w_z1[aB], tB, vz1));
      }
      size_t o = (size_t)(rowbase + r8) * 64 + lane;
      spb_s[o] = bf1(vs1);
      spb_t[o] = bf1(vt1);
      cres[o] = vres;
      cz0[o] = vz0;
      cz1[o] = vz1;
    }
  } else {
    // slow scan (never expected): absolute-row match
    float as1[4], at1[4], ares[4], az0[4], az1[4];
#pragma unroll
    for (int r = 0; r < 4; r++) { as1[r] = 0.f; at1[r] = 0.f; ares[r] = 0.f; az0[r] = 0.f; az1[r] = 0.f; }
    for (int a = 0; a < 4; a++) {
      int base = baseA[a], n = nA[a];
      for (int i = 0; i < n; i++) {
        int2 p = epk[base + i];
        int lr = p.x >> 17, c = p.x & 0x1FFFF;
        float v = __int_as_float(p.y);
        unsigned int g = xpb[(size_t)c * 64 + lane];
        float gs = v * bf_lo(g), gt = v * bf_hi(g);
#pragma unroll
        for (int r8 = 0; r8 < 4; r8++) {
          if (lr == bh * RBH + wv * 4 + r8) {
            as1[r8]  = fmaf(w_s1[a], gs, as1[r8]);
            ares[r8] = fmaf(w_res[a], gs, ares[r8]);
            az0[r8]  = fmaf(w_z0[a], gs, az0[r8]);
            at1[r8]  = fmaf(w_t1[a], gt, at1[r8]);
            az1[r8]  = fmaf(w_z1[a], gt, az1[r8]);
          }
        }
      }
    }
#pragma unroll
    for (int r8 = 0; r8 < 4; r8++) {
      size_t o = (size_t)(rowbase + r8) * 64 + lane;
      spb_s[o] = bf1(as1[r8]);
      spb_t[o] = bf1(at1[r8]);
      cres[o] = ares[r8];
      cz0[o] = az0[r8];
      cz1[o] = az1[r8];
    }
  }
}

// stage 2: gather split s1/t1 planes; t-plane only touched for adjs 0,1.
// read cres, emit s2b; accumulate cz0, cz1
__global__ __launch_bounds__(256, 8) void st2_kernel(
    const int* __restrict__ off2,
    const int* __restrict__ rofftab, const int2* __restrict__ epk,
    const unsigned short* __restrict__ spb_s, const unsigned short* __restrict__ spb_t,
    const float* __restrict__ as_seq0, const float* __restrict__ as_last_res0,
    const float* __restrict__ as_last_seq1,
    const float* __restrict__ cres, unsigned short* __restrict__ s2b,
    float* __restrict__ cz0, float* __restrict__ cz1) {
  __shared__ int2 se[4 * CAPH];   // .x = byte offset (col<<7), .y = val bits
  __shared__ int ro[4][RBH + 1];
  int bb = blockIdx.x;
  int b = bb >> 1, bh = bb & 1;
  int t = threadIdx.x, wv = t >> 6, lane = t & 63;
  float w_seq[4], w_z0[4], w_z1[4], tmp[4];
  sm3d(sload(as_seq0 + 3), sload(as_seq0 + 4), sload(as_seq0 + 5), 1.f / 3.f, tmp);
  w_seq[0] = tmp[0]; w_seq[1] = tmp[1]; w_seq[2] = tmp[2]; w_seq[3] = 0.f;
  sm3d(sload(as_last_res0 + 3), sload(as_last_res0 + 4), sload(as_last_res0 + 5),
       1.f / 3.f, tmp);
  w_z0[0] = tmp[0]; w_z0[1] = tmp[1]; w_z0[2] = 0.f; w_z0[3] = tmp[2];
  sm2d(sload(as_last_seq1 + 0), sload(as_last_seq1 + 1), 0.5f, tmp);
  w_z1[0] = tmp[0]; w_z1[1] = tmp[1]; w_z1[2] = 0.f; w_z1[3] = 0.f;

  int nA[4], baseA[4];
  bool fits = true;
#pragma unroll
  for (int a = 0; a < 4; a++) {
    int key = a * NB + b;
    int base = key_base(off2, key);
    int ntot = key_end(off2, key) - base;
    int rs, re;
    if (ntot <= CAP) {
      int mid = __builtin_amdgcn_readfirstlane(rofftab[(size_t)key * RB + RBH]);
      rs = bh ? mid : 0;
      re = bh ? ntot : mid;
    } else {
      rs = 0; re = ntot; fits = false;
    }
    baseA[a] = base + rs;
    nA[a] = re - rs;
    if (nA[a] > CAPH) fits = false;
  }
  int rowbase = b * RB + bh * RBH + wv * 4;
  if (fits) {
#pragma unroll
    for (int a = 0; a < 4; a++) {
      int n = nA[a], base = baseA[a];
      for (int i = t; i < n; i += 256) {
        int2 p = epk[base + i];
        se[a * CAPH + i] = make_int2((p.x & 0x1FFFF) << 7, p.y);
      }
    }
    if (t < 4 * (RBH + 1)) {
      int a = t / (RBH + 1), rr = t % (RBH + 1);
      int key = a * NB + b;
      int kb = off2[(size_t)key << 6];
      int ke = (key + 1 < NKEY) ? off2[(size_t)(key + 1) << 6] : (int)ME;
      int rs0 = bh ? rofftab[(size_t)key * RB + RBH] : 0;
      int ar = bh * RBH + rr;
      int v = (ar < RB) ? rofftab[(size_t)key * RB + ar] : (ke - kb);
      ro[a][rr] = v - rs0;
    }
    __syncthreads();
    const unsigned char* sbs = (const unsigned char*)spb_s;
    const unsigned char* sbt = (const unsigned char*)spb_t;
    unsigned lane2 = (unsigned)lane << 1;
    // both planes (adjs 0,1)
    auto tl2 = [&](const int2* sp, int i, int e, float& s0, float& s1,
                   float& t0, float& t1) {
      for (; i + 3 < e; i += 4) {
        int2 p0 = sp[i], p1 = sp[i + 1], p2 = sp[i + 2], p3 = sp[i + 3];
        float gs0 = bf_s(*(const unsigned short*)(sbs + ((unsigned)p0.x + lane2)));
        float gt0 = bf_s(*(const unsigned short*)(sbt + ((unsigned)p0.x + lane2)));
        float gs1 = bf_s(*(const unsigned short*)(sbs + ((unsigned)p1.x + lane2)));
        float gt1 = bf_s(*(const unsigned short*)(sbt + ((unsigned)p1.x + lane2)));
        float gs2 = bf_s(*(const unsigned short*)(sbs + ((unsigned)p2.x + lane2)));
        float gt2 = bf_s(*(const unsigned short*)(sbt + ((unsigned)p2.x + lane2)));
        float gs3 = bf_s(*(const unsigned short*)(sbs + ((unsigned)p3.x + lane2)));
        float gt3 = bf_s(*(const unsigned short*)(sbt + ((unsigned)p3.x + lane2)));
        float v0 = __int_as_float(p0.y), v1 = __int_as_float(p1.y);
        float v2 = __int_as_float(p2.y), v3 = __int_as_float(p3.y);
        s0 = fmaf(v0, gs0, s0); t0 = fmaf(v0, gt0, t0);
        s1 = fmaf(v1, gs1, s1); t1 = fmaf(v1, gt1, t1);
        s0 = fmaf(v2, gs2, s0); t0 = fmaf(v2, gt2, t0);
        s1 = fmaf(v3, gs3, s1); t1 = fmaf(v3, gt3, t1);
      }
      for (; i < e; i++) {
        int2 p = sp[i];
        float gs = bf_s(*(const unsigned short*)(sbs + ((unsigned)p.x + lane2)));
        float gt = bf_s(*(const unsigned short*)(sbt + ((unsigned)p.x + lane2)));
        float v = __int_as_float(p.y);
        s0 = fmaf(v, gs, s0); t0 = fmaf(v, gt, t0);
      }
    };
    // s-plane only (adjs 2,3: t-weights are structurally zero — half the bytes)
    auto tl1 = [&](const int2* sp, int i, int e, float& s0, float& s1) {
      for (; i + 3 < e; i += 4) {
        int2 p0 = sp[i], p1 = sp[i + 1], p2 = sp[i + 2], p3 = sp[i + 3];
        float g0 = bf_s(*(const unsigned short*)(sbs + ((unsigned)p0.x + lane2)));
        float g1 = bf_s(*(const unsigned short*)(sbs + ((unsigned)p1.x + lane2)));
        float g2 = bf_s(*(const unsigned short*)(sbs + ((unsigned)p2.x + lane2)));
        float g3 = bf_s(*(const unsigned short*)(sbs + ((unsigned)p3.x + lane2)));
        s0 = fmaf(__int_as_float(p0.y), g0, s0);
        s1 = fmaf(__int_as_float(p1.y), g1, s1);
        s0 = fmaf(__int_as_float(p2.y), g2, s0);
        s1 = fmaf(__int_as_float(p3.y), g3, s1);
      }
      for (; i < e; i++) {
        int2 p = sp[i];
        float g = bf_s(*(const unsigned short*)(sbs + ((unsigned)p.x + lane2)));
        s0 = fmaf(__int_as_float(p.y), g, s0);
      }
    };
    for (int r8 = 0; r8 < 4; r8++) {
      int r = wv * 4 + r8;
      float vres = 0.f, vz0 = 0.f, vz1 = 0.f;
      {  // pair (0,1): both planes live
        const int2* spA = se;
        const int2* spB = se + CAPH;
        int iA = ro[0][r], eA = ro[0][r + 1];
        int iB = ro[1][r], eB = ro[1][r + 1];
        float sA0 = 0.f, sA1 = 0.f, tA0 = 0.f, tA1 = 0.f;
        float sB0 = 0.f, sB1 = 0.f, tB0 = 0.f, tB1 = 0.f;
        int dA = eA - iA, dB = eB - iB;
        int m = (dA < dB ? dA : dB) >> 2;
        for (int k = 0; k < m; k++) {
          int2 a0 = spA[iA], a1 = spA[iA + 1], a2 = spA[iA + 2], a3 = spA[iA + 3];
          int2 b0 = spB[iB], b1 = spB[iB + 1], b2 = spB[iB + 2], b3 = spB[iB + 3];
          float gsA0 = bf_s(*(const unsigned short*)(sbs + ((unsigned)a0.x + lane2)));
          float gtA0 = bf_s(*(const unsigned short*)(sbt + ((unsigned)a0.x + lane2)));
          float gsA1 = bf_s(*(const unsigned short*)(sbs + ((unsigned)a1.x + lane2)));
          float gtA1 = bf_s(*(const unsigned short*)(sbt + ((unsigned)a1.x + lane2)));
          float gsA2 = bf_s(*(const unsigned short*)(sbs + ((unsigned)a2.x + lane2)));
          float gtA2 = bf_s(*(const unsigned short*)(sbt + ((unsigned)a2.x + lane2)));
          float gsA3 = bf_s(*(const unsigned short*)(sbs + ((unsigned)a3.x + lane2)));
          float gtA3 = bf_s(*(const unsigned short*)(sbt + ((unsigned)a3.x + lane2)));
          float gsB0 = bf_s(*(const unsigned short*)(sbs + ((unsigned)b0.x + lane2)));
          float gtB0 = bf_s(*(const unsigned short*)(sbt + ((unsigned)b0.x + lane2)));
          float gsB1 = bf_s(*(const unsigned short*)(sbs + ((unsigned)b1.x + lane2)));
          float gtB1 = bf_s(*(const unsigned short*)(sbt + ((unsigned)b1.x + lane2)));
          float gsB2 = bf_s(*(const unsigned short*)(sbs + ((unsigned)b2.x + lane2)));
          float gtB2 = bf_s(*(const unsigned short*)(sbt + ((unsigned)b2.x + lane2)));
          float gsB3 = bf_s(*(const unsigned short*)(sbs + ((unsigned)b3.x + lane2)));
          float gtB3 = bf_s(*(const unsigned short*)(sbt + ((unsigned)b3.x + lane2)));
          float vA0 = __int_as_float(a0.y), vA1 = __int_as_float(a1.y);
          float vA2 = __int_as_float(a2.y), vA3 = __int_as_float(a3.y);
          float vB0 = __int_as_float(b0.y), vB1 = __int_as_float(b1.y);
          float vB2 = __int_as_float(b2.y), vB3 = __int_as_float(b3.y);
          sA0 = fmaf(vA0, gsA0, sA0); tA0 = fmaf(vA0, gtA0, tA0);
          sA1 = fmaf(vA1, gsA1, sA1); tA1 = fmaf(vA1, gtA1, tA1);
          sA0 = fmaf(vA2, gsA2, sA0); tA0 = fmaf(vA2, gtA2, tA0);
          sA1 = fmaf(vA3, gsA3, sA1); tA1 = fmaf(vA3, gtA3, tA1);
          sB0 = fmaf(vB0, gsB0, sB0); tB0 = fmaf(vB0, gtB0, tB0);
          sB1 = fmaf(vB1, gsB1, sB1); tB1 = fmaf(vB1, gtB1, tB1);
          sB0 = fmaf(vB2, gsB2, sB0); tB0 = fmaf(vB2, gtB2, tB0);
          sB1 = fmaf(vB3, gsB3, sB1); tB1 = fmaf(vB3, gtB3, tB1);
          iA += 4; iB += 4;
        }
        tl2(spA, iA, eA, sA0, sA1, tA0, tA1);
        tl2(spB, iB, eB, sB0, sB1, tB0, tB1);
        float sA = sA0 + sA1, tA = tA0 + tA1;
        float sB = sB0 + sB1, tB = tB0 + tB1;
        vres = fmaf(w_seq[0], sA, fmaf(w_seq[1], sB, vres));
        vz0  = fmaf(w_z0[0], sA, fmaf(w_z0[1], sB, vz0));
        vz1  = fmaf(w_z1[0], tA, fmaf(w_z1[1], tB, vz1));
      }
      {  // pair (2,3): s-plane only
        const int2* spA = se + 2 * CAPH;
        const int2* spB = se + 3 * CAPH;
        int iA = ro[2][r], eA = ro[2][r + 1];
        int iB = ro[3][r], eB = ro[3][r + 1];
        float sA0 = 0.f, sA1 = 0.f, sB0 = 0.f, sB1 = 0.f;
        int dA = eA - iA, dB = eB - iB;
        int m = (dA < dB ? dA : dB) >> 2;
        for (int k = 0; k < m; k++) {
          int2 a0 = spA[iA], a1 = spA[iA + 1], a2 = spA[iA + 2], a3 = spA[iA + 3];
          int2 b0 = spB[iB], b1 = spB[iB + 1], b2 = spB[iB + 2], b3 = spB[iB + 3];
          float gA0 = bf_s(*(const unsigned short*)(sbs + ((unsigned)a0.x + lane2)));
          float gA1 = bf_s(*(const unsigned short*)(sbs + ((unsigned)a1.x + lane2)));
          float gA2 = bf_s(*(const unsigned short*)(sbs + ((unsigned)a2.x + lane2)));
          float gA3 = bf_s(*(const unsigned short*)(sbs + ((unsigned)a3.x + lane2)));
          float gB0 = bf_s(*(const unsigned short*)(sbs + ((unsigned)b0.x + lane2)));
          float gB1 = bf_s(*(const unsigned short*)(sbs + ((unsigned)b1.x + lane2)));
          float gB2 = bf_s(*(const unsigned short*)(sbs + ((unsigned)b2.x + lane2)));
          float gB3 = bf_s(*(const unsigned short*)(sbs + ((unsigned)b3.x + lane2)));
          sA0 = fmaf(__int_as_float(a0.y), gA0, sA0);
          sA1 = fmaf(__int_as_float(a1.y), gA1, sA1);
          sA0 = fmaf(__int_as_float(a2.y), gA2, sA0);
          sA1 = fmaf(__int_as_float(a3.y), gA3, sA1);
          sB0 = fmaf(__int_as_float(b0.y), gB0, sB0);
          sB1 = fmaf(__int_as_float(b1.y), gB1, sB1);
          sB0 = fmaf(__int_as_float(b2.y), gB2, sB0);
          sB1 = fmaf(__int_as_float(b3.y), gB3, sB1);
          iA += 4; iB += 4;
        }
        tl1(spA, iA, eA, sA0, sA1);
        tl1(spB, iB, eB, sB0, sB1);
        float sA = sA0 + sA1, sB = sB0 + sB1;
        vres = fmaf(w_seq[2], sA, fmaf(w_seq[3], sB, vres));
        vz0  = fmaf(w_z0[2], sA, fmaf(w_z0[3], sB, vz0));
      }
      size_t o = (size_t)(rowbase + r8) * 64 + lane;
      float s2v = cres[o] + vres;   // cres is dead after this kernel: no store-back
      s2b[o] = bf1(s2v);
      cz0[o] += vz0;
      cz1[o] += vz1;
    }
  } else {
    float dres[4], dz0[4], dz1[4];
#pragma unroll
    for (int r = 0; r < 4; r++) { dres[r] = 0.f; dz0[r] = 0.f; dz1[r] = 0.f; }
    for (int a = 0; a < 4; a++) {
      int base = baseA[a], n = nA[a];
      for (int i = 0; i < n; i++) {
        int2 p = epk[base + i];
        int lr = p.x >> 17, c = p.x & 0x1FFFF;
        float v = __int_as_float(p.y);
        float gs = v * bf_s(spb_s[(size_t)c * 64 + lane]);
        float gt = v * bf_s(spb_t[(size_t)c * 64 + lane]);
#pragma unroll
        for (int r8 = 0; r8 < 4; r8++) {
          if (lr == bh * RBH + wv * 4 + r8) {
            dres[r8] = fmaf(w_seq[a], gs, dres[r8]);
            dz0[r8]  = fmaf(w_z0[a], gs, dz0[r8]);
            dz1[r8]  = fmaf(w_z1[a], gt, dz1[r8]);
          }
        }
      }
    }
#pragma unroll
    for (int r8 = 0; r8 < 4; r8++) {
      size_t o = (size_t)(rowbase + r8) * 64 + lane;
      float s2v = cres[o] + dres[r8];
      s2b[o] = bf1(s2v);
      cz0[o] += dz0[r8];
      cz1[o] += dz1[r8];
    }
  }
}

// stage 3 + final fused: gather s2b (adjs 0,1), z0 = cz0 + dz kept in registers;
// epilogue de-shuffled: g staged in LDS (reusing se), uniform b128 broadcast reads.
__global__ __launch_bounds__(256, 8) void st3f_kernel(
    const int* __restrict__ off2,
    const int* __restrict__ rofftab, const int2* __restrict__ epk,
    const unsigned short* __restrict__ s2b, const float* __restrict__ as_last_seq0,
    const float* __restrict__ cz0, const float* __restrict__ cz1,
    const float* __restrict__ attn1_W, const float* __restrict__ attn1_b,
    const float* __restrict__ attn2_W, const float* __restrict__ attn2_b,
    const float* __restrict__ cls_W, const float* __restrict__ cls_b,
    float* __restrict__ out) {
  __shared__ int2 se[2 * CAPH];   // gather: (byte off, val); epilogue: reused as g-store
  __shared__ int ro[2][RBH + 1];
  __shared__ float2 psh[4][4];    // per wave, per row: {p0, p1}
  int bb = blockIdx.x;
  int b = bb >> 1, bh = bb & 1;
  int t = threadIdx.x, wv = t >> 6, lane = t & 63;
  float wA[2];
  sm2d(sload(as_last_seq0 + 0), sload(as_last_seq0 + 1), 0.5f, wA);
  float wA0 = wA[0], wA1 = wA[1];
  int nA[2], baseA[2];
  bool fits = true;   // block-uniform (derived via readfirstlane)
#pragma unroll
  for (int a = 0; a < 2; a++) {
    int key = a * NB + b;
    int base = key_base(off2, key);
    int ntot = key_end(off2, key) - base;
    int rs, re;
    if (ntot <= CAP) {
      int mid = __builtin_amdgcn_readfirstlane(rofftab[(size_t)key * RB + RBH]);
      rs = bh ? mid : 0;
      re = bh ? ntot : mid;
    } else {
      rs = 0; re = ntot; fits = false;
    }
    baseA[a] = base + rs;
    nA[a] = re - rs;
    if (nA[a] > CAPH) fits = false;
  }
  int rowbase = b * RB + bh * RBH + wv * 4;
  float dz[4];
#pragma unroll
  for (int r = 0; r < 4; r++) dz[r] = 0.f;
  if (fits) {
#pragma unroll
    for (int a = 0; a < 2; a++) {
      int n = nA[a], base = baseA[a];
      for (int i = t; i < n; i += 256) {
        int2 p = epk[base + i];
        se[a * CAPH + i] = make_int2((p.x & 0x1FFFF) << 7, p.y);
      }
    }
    if (t < 2 * (RBH + 1)) {
      int a = t / (RBH + 1), rr = t % (RBH + 1);
      int key = a * NB + b;
      int kb = off2[(size_t)key << 6];
      int ke = (key + 1 < NKEY) ? off2[(size_t)(key + 1) << 6] : (int)ME;
      int rs0 = bh ? rofftab[(size_t)key * RB + RBH] : 0;
      int ar = bh * RBH + rr;
      int v = (ar < RB) ? rofftab[(size_t)key * RB + ar] : (ke - kb);
      ro[a][rr] = v - rs0;
    }
    __syncthreads();
    const unsigned char* sb = (const unsigned char*)s2b;
    unsigned lane2 = (unsigned)lane << 1;
    auto tlu = [&](const int2* sp, int i, int e, float& s0, float& s1) {
      for (; i + 3 < e; i += 4) {
        int2 p0 = sp[i], p1 = sp[i + 1], p2 = sp[i + 2], p3 = sp[i + 3];
        float g0 = bf_s(*(const unsigned short*)(sb + ((unsigned)p0.x + lane2)));
        float g1 = bf_s(*(const unsigned short*)(sb + ((unsigned)p1.x + lane2)));
        float g2 = bf_s(*(const unsigned short*)(sb + ((unsigned)p2.x + lane2)));
        float g3 = bf_s(*(const unsigned short*)(sb + ((unsigned)p3.x + lane2)));
        s0 = fmaf(__int_as_float(p0.y), g0, s0);
        s1 = fmaf(__int_as_float(p1.y), g1, s1);
        s0 = fmaf(__int_as_float(p2.y), g2, s0);
        s1 = fmaf(__int_as_float(p3.y), g3, s1);
      }
      for (; i < e; i++) {
        int2 p = sp[i];
        float g = bf_s(*(const unsigned short*)(sb + ((unsigned)p.x + lane2)));
        s0 = fmaf(__int_as_float(p.y), g, s0);
      }
    };
    for (int r8 = 0; r8 < 4; r8++) {
      int r = wv * 4 + r8;
      const int2* spA = se;
      const int2* spB = se + CAPH;
      int iA = ro[0][r], eA = ro[0][r + 1];
      int iB = ro[1][r], eB = ro[1][r + 1];
      float sA0 = 0.f, sA1 = 0.f, sB0 = 0.f, sB1 = 0.f;
      int dA = eA - iA, dB = eB - iB;
      int m = (dA < dB ? dA : dB) >> 2;
      for (int k = 0; k < m; k++) {
        int2 a0 = spA[iA], a1 = spA[iA + 1], a2 = spA[iA + 2], a3 = spA[iA + 3];
        int2 b0 = spB[iB], b1 = spB[iB + 1], b2 = spB[iB + 2], b3 = spB[iB + 3];
        float gA0 = bf_s(*(const unsigned short*)(sb + ((unsigned)a0.x + lane2)));
        float gA1 = bf_s(*(const unsigned short*)(sb + ((unsigned)a1.x + lane2)));
        float gA2 = bf_s(*(const unsigned short*)(sb + ((unsigned)a2.x + lane2)));
        float gA3 = bf_s(*(const unsigned short*)(sb + ((unsigned)a3.x + lane2)));
        float gB0 = bf_s(*(const unsigned short*)(sb + ((unsigned)b0.x + lane2)));
        float gB1 = bf_s(*(const unsigned short*)(sb + ((unsigned)b1.x + lane2)));
        float gB2 = bf_s(*(const unsigned short*)(sb + ((unsigned)b2.x + lane2)));
        float gB3 = bf_s(*(const unsigned short*)(sb + ((unsigned)b3.x + lane2)));
        sA0 = fmaf(__int_as_float(a0.y), gA0, sA0);
        sA1 = fmaf(__int_as_float(a1.y), gA1, sA1);
        sA0 = fmaf(__int_as_float(a2.y), gA2, sA0);
        sA1 = fmaf(__int_as_float(a3.y), gA3, sA1);
        sB0 = fmaf(__int_as_float(b0.y), gB0, sB0);
        sB1 = fmaf(__int_as_float(b1.y), gB1, sB1);
        sB0 = fmaf(__int_as_float(b2.y), gB2, sB0);
        sB1 = fmaf(__int_as_float(b3.y), gB3, sB1);
        iA += 4; iB += 4;
      }
      tlu(spA, iA, eA, sA0, sA1);
      tlu(spB, iB, eB, sB0, sB1);
      dz[r8] = fmaf(wA0, sA0 + sA1, wA1 * (sB0 + sB1));
    }
  } else {
    for (int a = 0; a < 2; a++) {
      int base = baseA[a], n = nA[a];
      float wa = a ? wA1 : wA0;
      for (int i = 0; i < n; i++) {
        int2 p = epk[base + i];
        int lr = p.x >> 17, c = p.x & 0x1FFFF;
        float v = __int_as_float(p.y);
        float gs = v * bf_s(s2b[(size_t)c * 64 + lane]);
#pragma unroll
        for (int r8 = 0; r8 < 4; r8++) {
          if (lr == bh * RBH + wv * 4 + r8) dz[r8] = fmaf(wa, gs, dz[r8]);
        }
      }
    }
  }

  // ---- fused epilogue (de-shuffled): all waves done with se; reuse as g-store ----
  __syncthreads();
  float2* gsh = (float2*)se;            // [4 waves][4 rows][64] float2 {g0,g1} = 8 KB
  float aw = attn2_W[lane];
  float ab = attn1_b[lane];
  float a2b = sload(attn2_b);

  // phase A: LN + gelu per row; stash {g0,g1} pairs (1 ds_write_b64/row)
  for (int r8 = 0; r8 < 4; r8++) {
    size_t o = (size_t)(rowbase + r8) * 64 + lane;
    float z0 = cz0[o] + dz[r8];
    float z1 = cz1[o];

    float m0 = wave_bsum(z0) * (1.f / 64.f);
    float dv0 = z0 - m0;
    float var0 = wave_bsum(dv0 * dv0) * (1.f / 64.f);
    float y0 = dv0 * rsqrtf(var0 + 1e-5f);
    float g0 = 0.5f * y0 * (1.f + erff(y0 * 0.70710678118654752f));

    float m1 = wave_bsum(z1) * (1.f / 64.f);
    float dv1 = z1 - m1;
    float var1 = wave_bsum(dv1 * dv1) * (1.f / 64.f);
    float y1 = dv1 * rsqrtf(var1 + 1e-5f);
    float g1 = 0.5f * y1 * (1.f + erff(y1 * 0.70710678118654752f));

    gsh[((size_t)wv * 4 + r8) * 64 + lane] = make_float2(g0, g1);
  }

  // phase B: joint 4-row attn1 matvec via uniform-address b128 broadcast reads.
  // j-order identical to the old shfl loop -> t0/t1 bit-exact.
  float t0[4], t1[4];
#pragma unroll
  for (int r = 0; r < 4; r++) { t0[r] = ab; t1[r] = ab; }
  const float4* gq = (const float4*)(gsh + (size_t)wv * 4 * 64);  // 32 float4 per row
  for (int j2 = 0; j2 < 64; j2 += 2) {
    float w0 = attn1_W[j2 * HD + lane];
    float w1 = attn1_W[(j2 + 1) * HD + lane];
#pragma unroll
    for (int r = 0; r < 4; r++) {
      float4 gg = gq[r * 32 + (j2 >> 1)];   // {g0_j2, g1_j2, g0_j2+1, g1_j2+1}
      t0[r] = fmaf(gg.x, w0, t0[r]);
      t1[r] = fmaf(gg.y, w0, t1[r]);
      t0[r] = fmaf(gg.z, w1, t0[r]);
      t1[r] = fmaf(gg.w, w1, t1[r]);
    }
  }

  // phase C: per-row attention scores + softmax; stash {p0,p1}
  for (int r = 0; r < 4; r++) {
    float tt0 = tanhf(t0[r]);
    float tt1 = tanhf(t1[r]);
    float a0 = wave_bsum(tt0 * aw) + a2b;
    float a1 = wave_bsum(tt1 * aw) + a2b;
    float mx = fmaxf(a0, a1);
    float e0 = expf(a0 - mx), e1 = expf(a1 - mx);
    float inv = 1.f / (e0 + e1);
    if (lane == 0) psh[wv][r] = make_float2(e0 * inv, e1 * inv);
  }

  // phase D: classifier. out = p0*(g0@C) + p1*(g1@C) + b.
  // lanes 0..31: (row, class) = (lane>>3, lane&7); coalesced 128B store.
  if (lane < 32) {
    int r = lane >> 3, k = lane & 7;
    float2 pp = psh[wv][r];
    const float4* gr = (const float4*)(gsh + ((size_t)wv * 4 + r) * 64);
    float u0 = 0.f, u1 = 0.f;
    for (int j2 = 0; j2 < 32; j2++) {
      float4 gg = gr[j2];                 // {g0_j, g1_j, g0_j+1, g1_j+1}
      int j = j2 * 2;
      float c0 = cls_W[j * 8 + k];
      float c1 = cls_W[(j + 1) * 8 + k];
      u0 = fmaf(gg.x, c0, u0); u1 = fmaf(gg.y, c0, u1);
      u0 = fmaf(gg.z, c1, u0); u1 = fmaf(gg.w, c1, u1);
    }
    int n = rowbase + r;
    out[(size_t)n * 8 + k] = fmaf(pp.x, u0, pp.y * u1) + cls_b[k];
  }
}

extern "C" void kernel_launch(void* const* d_in, const int* in_sizes, int n_in,
                              void* d_out, int out_size, void* d_ws, size_t ws_size,
                              hipStream_t stream) {
  const float* node_feats   = (const float*)d_in[0];
  const int*   node_types   = (const int*)d_in[1];
  const int*   adj_rows     = (const int*)d_in[2];
  const int*   adj_cols     = (const int*)d_in[3];
  const float* adj_vals     = (const float*)d_in[4];
  const float* type_W       = (const float*)d_in[5];
  const float* type_b       = (const float*)d_in[6];
  const float* aW0          = (const float*)d_in[7];
  const float* ab0          = (const float*)d_in[8];
  const float* aW1          = (const float*)d_in[9];
  const float* ab1          = (const float*)d_in[10];
  const float* as_seq0      = (const float*)d_in[11];
  const float* as_last_seq0 = (const float*)d_in[12];
  const float* as_res0      = (const float*)d_in[13];
  const float* as_last_res0 = (const float*)d_in[14];
  const float* as_seq1      = (const float*)d_in[15];
  const float* as_last_seq1 = (const float*)d_in[16];
  const float* as_last_res1 = (const float*)d_in[17];
  const float* attn1_W      = (const float*)d_in[18];
  const float* attn1_b      = (const float*)d_in[19];
  const float* attn2_W      = (const float*)d_in[20];
  const float* attn2_b      = (const float*)d_in[21];
  const float* cls_W        = (const float*)d_in[22];
  const float* cls_b        = (const float*)d_in[23];
  float* out = (float*)d_out;
  float* ws = (float*)d_ws;

  unsigned int*   xpb   = (unsigned int*)(ws + XPB_OFF);
  unsigned short* spb_s = (unsigned short*)(ws + SPB_OFF);
  unsigned short* spb_t = (unsigned short*)(ws + SPB_OFF + NP / 2);
  float*          cres  = ws + CRES_OFF;
  float*          cz0   = ws + CZ0_OFF;
  float*          cz1   = ws + CZ1_OFF;
  unsigned short* s2b   = (unsigned short*)(ws + S2B_OFF);
  int2*           epk   = (int2*)(ws + EPK_OFF);
  int*            cnt2  = (int*)(ws + CNT2_OFF);
  int*            off2  = (int*)(ws + OFF2_OFF);
  int*            part  = (int*)(ws + PART_OFF);
  int*            roff  = (int*)(ws + ROFF_OFF);
  int*            ncnt  = (int*)(ws + NCNT_OFF);
  int*            noff  = (int*)(ws + NOFF_OFF);
  int*            nperm = (int*)(ws + NPERM_OFF);

  // node type sort + typed projection (8 same-type nodes per wave)
  nhist_kernel<<<NCH, 256, 0, stream>>>(node_types, ncnt);
  nscan_kernel<<<1, 256, 0, stream>>>(ncnt, noff);
  nscatter_kernel<<<NCH, 256, 0, stream>>>(node_types, noff, nperm);
  hid2_kernel<<<NNODES / 32, 256, 0, stream>>>(node_feats, node_types, nperm,
                                               type_W, type_b, aW0, ab0, aW1, ab1, xpb);

  // deterministic edge build: hist2 -> scan -> LDS-cursor scatter -> pack+sort
  histb2_kernel<<<dim3(CHK, 4), 256, 0, stream>>>(adj_rows, cnt2);
  scan1_kernel<<<SCAN1B, 256, 0, stream>>>(cnt2, off2, part);
  scan2_kernel<<<1, 1024, 0, stream>>>(part);
  scan3_kernel<<<SCAN1B, 256, 0, stream>>>(off2, part);
  scatterd_kernel<<<dim3(CHK, 4), 256, 0, stream>>>(adj_rows, adj_cols, adj_vals, off2, epk);
  pack_kernel<<<NKEY, 256, 0, stream>>>(off2, epk, roff);

  // SpMM stages (arch-weight softmaxes computed inline; keyoff inlined from off2)
  st1_kernel<<<NB * 2, 256, 0, stream>>>(off2, roff, epk, xpb,
                                         as_seq0, as_res0, as_last_res0, as_seq1,
                                         as_last_res1,
                                         spb_s, spb_t, cres, cz0, cz1);
  st2_kernel<<<NB * 2, 256, 0, stream>>>(off2, roff, epk, spb_s, spb_t,
                                         as_seq0, as_last_res0, as_last_seq1,
                                         cres, s2b, cz0, cz1);
  // stage 3 + final fused (de-shuffled epilogue; writes logits directly)
  st3f_kernel<<<NB * 2, 256, 0, stream>>>(off2, roff, epk, s2b, as_last_seq0,
                                          cz0, cz1,
                                          attn1_W, attn1_b, attn2_W, attn2_b,
                                          cls_W, cls_b, out);
}

// Round 8
// 1317.170 us; speedup vs baseline: 2.4072x; 2.4072x over previous
//
#include <hip/hip_runtime.h>
#include <math.h>

// Problem constants (match reference file)
#define NNODES 100000
#define NEDGE  1600000
#define HD     64
#define INDIM  256

#define RB   32                 // rows per bucket
#define RBH  16                 // rows per half-bucket (stage kernels)
#define NB   3125               // NNODES / RB (exact)
#define NKEY (4 * NB)           // 12500 (a, bucket) regions
#define CAP  1024               // pack LDS capacity
#define CAPH 512                // per-adjacency stage slot per half-bucket (mean 256, +16 sigma)
#define CHK  64                 // chunks per adjacency (deterministic scatter)
#define EPC  (NEDGE / CHK)      // 25000 edges per chunk
#define NCH  100                // node chunks (type sort)
#define NPC  (NNODES / NCH)     // 1000 nodes per chunk

static constexpr size_t NP = (size_t)NNODES * HD;   // 6.4M elems per [N,H] plane
static constexpr size_t ME = (size_t)4 * NEDGE;     // 6.4M edges total
static constexpr int    M2 = NKEY * CHK;            // 800000 (key,chunk) counters
static constexpr int    SCAN1B = (M2 + 1023) / 1024;  // 782

// workspace layout (floats) — total ~200.5 MB
static constexpr size_t XPB_OFF   = 0;                   // uint bf16x2 (x0,x1): NP
static constexpr size_t SPB_OFF   = NP;                  // ushort s1 plane: NP/2 floats; ushort t1 plane: NP/2 floats
static constexpr size_t CRES_OFF  = 2 * NP;              // s2 accumulator (f32)
static constexpr size_t CZ0_OFF   = 3 * NP;              // z0 (f32)
static constexpr size_t CZ1_OFF   = 4 * NP;              // z1 (f32)
static constexpr size_t S2B_OFF   = 5 * NP;              // ushort bf16 s2: NP/2 floats
static constexpr size_t EPK_OFF   = 5 * NP + NP / 2;     // int2 (lr|col,val): 2*ME
static constexpr size_t CNT2_OFF  = EPK_OFF + 2 * ME;    // M2 ints [key][chunk]
static constexpr size_t OFF2_OFF  = CNT2_OFF + M2;       // M2 ints
static constexpr size_t PART_OFF  = OFF2_OFF + M2;       // 1024 ints
static constexpr size_t ROFF_OFF  = PART_OFF + 1024;     // NKEY*RB ints
static constexpr size_t NCNT_OFF  = ROFF_OFF + (size_t)NKEY * RB;  // 512 ints
static constexpr size_t NOFF_OFF  = NCNT_OFF + 512;      // 512 ints
static constexpr size_t NPERM_OFF = NOFF_OFF + 512;      // NNODES ints

// ---------------- helpers ----------------
__device__ __forceinline__ float wave_bsum(float v) {
#pragma unroll
  for (int m = 1; m < 64; m <<= 1) v += __shfl_xor(v, m, 64);
  return v;
}

__device__ __forceinline__ unsigned int bf2pack(float a, float b) {
  unsigned int ua = __float_as_uint(a);
  ua += 0x7FFFu + ((ua >> 16) & 1u);        // RNE
  unsigned int ub = __float_as_uint(b);
  ub += 0x7FFFu + ((ub >> 16) & 1u);
  return (ua >> 16) | (ub & 0xFFFF0000u);
}
__device__ __forceinline__ unsigned short bf1(float a) {
  unsigned int ua = __float_as_uint(a);
  ua += 0x7FFFu + ((ua >> 16) & 1u);
  return (unsigned short)(ua >> 16);
}
__device__ __forceinline__ float bf_lo(unsigned int g) { return __uint_as_float(g << 16); }
__device__ __forceinline__ float bf_hi(unsigned int g) { return __uint_as_float(g & 0xFFFF0000u); }
__device__ __forceinline__ float bf_s(unsigned short g) {
  return __uint_as_float((unsigned int)g << 16);
}
// force a uniform float load into an SGPR (keeps weight tables out of the VGPR budget)
__device__ __forceinline__ float sload(const float* p) {
  return __uint_as_float(__builtin_amdgcn_readfirstlane(__float_as_uint(*p)));
}
// softmax coefficient helpers (identical math to the old wcoef kernel)
__device__ __forceinline__ void sm3d(float a0, float a1, float a2, float sc, float* o) {
  float m = fmaxf(a0, fmaxf(a1, a2));
  float e0 = expf(a0 - m), e1 = expf(a1 - m), e2 = expf(a2 - m);
  float inv = sc / (e0 + e1 + e2);
  o[0] = e0 * inv; o[1] = e1 * inv; o[2] = e2 * inv;
}
__device__ __forceinline__ void sm2d(float a0, float a1, float sc, float* o) {
  float m = fmaxf(a0, a1);
  float e0 = expf(a0 - m), e1 = expf(a1 - m);
  float inv = sc / (e0 + e1);
  o[0] = e0 * inv; o[1] = e1 * inv;
}
__device__ __forceinline__ void sm4d(float a0, float a1, float a2, float a3, float sc, float* o) {
  float m = fmaxf(fmaxf(a0, a1), fmaxf(a2, a3));
  float e0 = expf(a0 - m), e1 = expf(a1 - m), e2 = expf(a2 - m), e3 = expf(a3 - m);
  float inv = sc / (e0 + e1 + e2 + e3);
  o[0] = e0 * inv; o[1] = e1 * inv; o[2] = e2 * inv; o[3] = e3 * inv;
}

// ================= node type sort (deterministic, chunked) =================
__global__ __launch_bounds__(256) void nhist_kernel(const int* __restrict__ types,
                                                    int* __restrict__ ncnt) {
  __shared__ int c[4];
  int ch = blockIdx.x;
  if (threadIdx.x < 4) c[threadIdx.x] = 0;
  __syncthreads();
  int base = ch * NPC;
  for (int i = base + threadIdx.x; i < base + NPC; i += 256)
    atomicAdd(&c[types[i]], 1);
  __syncthreads();
  if (threadIdx.x < 4) ncnt[threadIdx.x * NCH + ch] = c[threadIdx.x];
}

__global__ __launch_bounds__(256) void nscan_kernel(const int* __restrict__ ncnt,
                                                    int* __restrict__ noff) {
  __shared__ int sdata[256];
  int t = threadIdx.x;
  int i0 = t * 2;
  int v0 = (i0 < 4 * NCH) ? ncnt[i0] : 0;
  int v1 = (i0 + 1 < 4 * NCH) ? ncnt[i0 + 1] : 0;
  int ts = v0 + v1;
  sdata[t] = ts;
  __syncthreads();
  for (int o = 1; o < 256; o <<= 1) {
    int x = (t >= o) ? sdata[t - o] : 0;
    __syncthreads();
    sdata[t] += x;
    __syncthreads();
  }
  int excl = sdata[t] - ts;
  if (i0 < 4 * NCH) noff[i0] = excl;
  if (i0 + 1 < 4 * NCH) noff[i0 + 1] = excl + v0;
}

__global__ __launch_bounds__(256) void nscatter_kernel(const int* __restrict__ types,
                                                       const int* __restrict__ noff,
                                                       int* __restrict__ nperm) {
  __shared__ int cur[4];
  int ch = blockIdx.x;
  if (threadIdx.x < 4) cur[threadIdx.x] = noff[threadIdx.x * NCH + ch];
  __syncthreads();
  int base = ch * NPC;
  for (int i = base + threadIdx.x; i < base + NPC; i += 256) {
    int pos = atomicAdd(&cur[types[i]], 1);
    nperm[pos] = i;
  }
}

// ---------------- typed projection + both affines, type-sorted, 8 nodes/wave ----------------
__global__ __launch_bounds__(256) void hid2_kernel(
    const float* __restrict__ feats, const int* __restrict__ types,
    const int* __restrict__ nperm,
    const float* __restrict__ type_W, const float* __restrict__ type_b,
    const float* __restrict__ W0, const float* __restrict__ b0,
    const float* __restrict__ W1, const float* __restrict__ b1,
    unsigned int* __restrict__ xpb) {
  __shared__ float sh_h[4][8][64];
  int t = threadIdx.x, wv = t >> 6, lane = t & 63;
  int idx0 = blockIdx.x * 32 + wv * 8;
  int nj[8];
#pragma unroll
  for (int j = 0; j < 8; j++)
    nj[j] = __builtin_amdgcn_readfirstlane(nperm[idx0 + j]);
  int t0 = __builtin_amdgcn_readfirstlane(types[nj[0]]);
  int t7 = __builtin_amdgcn_readfirstlane(types[nj[7]]);
  float acc[8];
  if (t0 == t7) {
    const float* W = type_W + (size_t)t0 * (INDIM * HD);
    float bias = type_b[t0 * HD + lane];
#pragma unroll
    for (int j = 0; j < 8; j++) acc[j] = bias;
    for (int k = 0; k < INDIM; k += 4) {
#pragma unroll
      for (int kk = 0; kk < 4; kk++) {
        float wk = W[(k + kk) * HD + lane];
#pragma unroll
        for (int j = 0; j < 8; j++)
          acc[j] = fmaf(feats[(size_t)nj[j] * INDIM + k + kk], wk, acc[j]);
      }
    }
  } else {
    for (int j = 0; j < 8; j++) {
      int tj = __builtin_amdgcn_readfirstlane(types[nj[j]]);
      const float* W = type_W + (size_t)tj * (INDIM * HD);
      float a = type_b[tj * HD + lane];
      for (int k = 0; k < INDIM; k++)
        a = fmaf(feats[(size_t)nj[j] * INDIM + k], W[k * HD + lane], a);
      acc[j] = a;
    }
  }
#pragma unroll
  for (int j = 0; j < 8; j++) sh_h[wv][j][lane] = acc[j];
  float a0[8], a1[8];
  float bb0 = b0[lane], bb1 = b1[lane];
#pragma unroll
  for (int j = 0; j < 8; j++) { a0[j] = bb0; a1[j] = bb1; }
  for (int j2 = 0; j2 < 64; j2++) {
    float w0 = W0[j2 * HD + lane], w1 = W1[j2 * HD + lane];
#pragma unroll
    for (int j = 0; j < 8; j++) {
      float hv = sh_h[wv][j][j2];
      a0[j] = fmaf(hv, w0, a0[j]);
      a1[j] = fmaf(hv, w1, a1[j]);
    }
  }
#pragma unroll
  for (int j = 0; j < 8; j++)
    xpb[(size_t)nj[j] * HD + lane] = bf2pack(a0[j], a1[j]);
}

// ================= deterministic two-pass edge build (no global atomics) =================
__global__ __launch_bounds__(256) void histb2_kernel(const int* __restrict__ rows,
                                                     int* __restrict__ cnt2) {
  __shared__ int h[NB];
  int a = blockIdx.y, ch = blockIdx.x;
  for (int i = threadIdx.x; i < NB; i += 256) h[i] = 0;
  __syncthreads();
  int base = ch * EPC;
  for (int e = base + threadIdx.x; e < base + EPC; e += 256)
    atomicAdd(&h[rows[(size_t)a * NEDGE + e] >> 5], 1);
  __syncthreads();
  for (int b = threadIdx.x; b < NB; b += 256)
    cnt2[((size_t)(a * NB + b) << 6) | ch] = h[b];
}

__global__ __launch_bounds__(256) void scan1_kernel(const int* __restrict__ cnt2,
                                                    int* __restrict__ off2,
                                                    int* __restrict__ part) {
  __shared__ int sdata[256];
  int t = threadIdx.x;
  int base = blockIdx.x * 1024 + t * 4;
  int v0 = (base + 0 < M2) ? cnt2[base + 0] : 0;
  int v1 = (base + 1 < M2) ? cnt2[base + 1] : 0;
  int v2 = (base + 2 < M2) ? cnt2[base + 2] : 0;
  int v3 = (base + 3 < M2) ? cnt2[base + 3] : 0;
  int tsum = v0 + v1 + v2 + v3;
  sdata[t] = tsum;
  __syncthreads();
  for (int o = 1; o < 256; o <<= 1) {
    int x = (t >= o) ? sdata[t - o] : 0;
    __syncthreads();
    sdata[t] += x;
    __syncthreads();
  }
  int excl = sdata[t] - tsum;
  if (t == 255) part[blockIdx.x] = sdata[255];
  if (base + 0 < M2) off2[base + 0] = excl;
  if (base + 1 < M2) off2[base + 1] = excl + v0;
  if (base + 2 < M2) off2[base + 2] = excl + v0 + v1;
  if (base + 3 < M2) off2[base + 3] = excl + v0 + v1 + v2;
}

__global__ __launch_bounds__(1024) void scan2_kernel(int* __restrict__ part) {
  __shared__ int sdata[1024];
  int t = threadIdx.x;
  int v = (t < SCAN1B) ? part[t] : 0;
  sdata[t] = v;
  __syncthreads();
  for (int o = 1; o < 1024; o <<= 1) {
    int x = (t >= o) ? sdata[t - o] : 0;
    __syncthreads();
    sdata[t] += x;
    __syncthreads();
  }
  if (t < SCAN1B) part[t] = sdata[t] - v;  // exclusive
}

__global__ __launch_bounds__(256) void scan3_kernel(int* __restrict__ off2,
                                                    const int* __restrict__ part) {
  int p = part[blockIdx.x];
  int t = threadIdx.x;
#pragma unroll
  for (int j = 0; j < 4; j++) {
    int i = blockIdx.x * 1024 + j * 256 + t;
    if (i < M2) off2[i] += p;
  }
}

// pass 2: deterministic scatter of packed (lr|col,val) using LDS cursors
__global__ __launch_bounds__(256) void scatterd_kernel(
    const int* __restrict__ rows, const int* __restrict__ cols, const float* __restrict__ vals,
    const int* __restrict__ off2, int2* __restrict__ epk) {
  __shared__ int cur[NB];
  int a = blockIdx.y, ch = blockIdx.x;
  for (int b = threadIdx.x; b < NB; b += 256)
    cur[b] = off2[((size_t)(a * NB + b) << 6) | ch];
  __syncthreads();
  int base = ch * EPC;
  for (int e = base + threadIdx.x; e < base + EPC; e += 256) {
    size_t idx = (size_t)a * NEDGE + e;
    int r = rows[idx];
    int pos = atomicAdd(&cur[r >> 5], 1);
    epk[pos] = make_int2(((r & 31) << 17) | cols[idx], __float_as_int(vals[idx]));
  }
}

// pack: per bucket, coalesced read epk region, counting-sort by local row in LDS,
// write back sorted + rofftab  (key offsets computed from off2 directly)
__global__ __launch_bounds__(256) void pack_kernel(
    const int* __restrict__ off2,
    int2* __restrict__ epk, int* __restrict__ rofftab) {
  __shared__ int smeta[CAP];
  __shared__ float sval[CAP];
  __shared__ int h[RB], hc[RB];
  int key = blockIdx.x;
  int base = off2[(size_t)key << 6];
  int kend = (key + 1 < NKEY) ? off2[(size_t)(key + 1) << 6] : (int)ME;
  int n = kend - base;
  int t = threadIdx.x, wv = t >> 6, lane = t & 63;
  if (t < RB) h[t] = 0;
  __syncthreads();
  if (n <= CAP) {
    int lm[4]; float lv[4];
    int cl = 0;
#pragma unroll
    for (int j = 0; j < 4; j++) {
      int i = t + j * 256;
      if (i < n) {
        int2 p = epk[base + i];
        lm[cl] = p.x;
        lv[cl] = __int_as_float(p.y);
        cl++;
        atomicAdd(&h[p.x >> 17], 1);
      }
    }
    __syncthreads();
    if (wv == 0) {
      int v = (lane < RB) ? h[lane] : 0;
      int incl = v;
#pragma unroll
      for (int o = 1; o < RB; o <<= 1) {
        int x = __shfl_up(incl, o, 64);
        if (lane >= o) incl += x;
      }
      if (lane < RB) {
        int excl = incl - v;
        hc[lane] = excl;
        rofftab[(size_t)key * RB + lane] = excl;
      }
    }
    __syncthreads();
    for (int j = 0; j < cl; j++) {
      int p = atomicAdd(&hc[lm[j] >> 17], 1);
      smeta[p] = lm[j];
      sval[p] = lv[j];
    }
    __syncthreads();
    for (int i = t; i < n; i += 256)
      epk[base + i] = make_int2(smeta[i], __float_as_int(sval[i]));
  }
  // n > CAP: leave unsorted; stages use slow scan path (never expected)
}

// ================= SpMM stages: half-bucket blocks, 4 rows/wave, joint-pair gathers =====

// region lookup from off2 (keyoff kernel inlined)
__device__ __forceinline__ int key_base(const int* off2, int key) {
  return __builtin_amdgcn_readfirstlane(off2[(size_t)key << 6]);
}
__device__ __forceinline__ int key_end(const int* off2, int key) {
  return (key + 1 < NKEY)
             ? __builtin_amdgcn_readfirstlane(off2[(size_t)(key + 1) << 6])
             : (int)ME;
}

// stage 1: gather xpb (bf16 x0,x1); write spb_s/spb_t (split bf16 planes), cres, cz0, cz1
__global__ __launch_bounds__(256, 8) void st1_kernel(
    const int* __restrict__ off2,
    const int* __restrict__ rofftab, const int2* __restrict__ epk,
    const unsigned int* __restrict__ xpb,
    const float* __restrict__ as_seq0, const float* __restrict__ as_res0,
    const float* __restrict__ as_last_res0, const float* __restrict__ as_seq1,
    const float* __restrict__ as_last_res1,
    unsigned short* __restrict__ spb_s, unsigned short* __restrict__ spb_t,
    float* __restrict__ cres, float* __restrict__ cz0, float* __restrict__ cz1) {
  __shared__ int2 se[4 * CAPH];     // .x = byte offset (col<<8), .y = val bits
  __shared__ int ro[4][RBH + 1];
  int bb = blockIdx.x;
  int b = bb >> 1, bh = bb & 1;
  int t = threadIdx.x, wv = t >> 6, lane = t & 63;
  // arch weights (wcoef inlined, identical math)
  float w_s1[4], w_res[4], w_z0[4], w_t1[4], w_z1[4], tmp[4];
  sm3d(sload(as_seq0 + 0), sload(as_seq0 + 1), sload(as_seq0 + 2), 1.f / 3.f, tmp);
  w_s1[0] = tmp[0]; w_s1[1] = tmp[1]; w_s1[2] = tmp[2]; w_s1[3] = 0.f;
  sm4d(sload(as_res0 + 0), sload(as_res0 + 1), sload(as_res0 + 2), sload(as_res0 + 3),
       0.25f, w_res);
  sm3d(sload(as_last_res0 + 0), sload(as_last_res0 + 1), sload(as_last_res0 + 2),
       1.f / 3.f, tmp);
  w_z0[0] = tmp[0]; w_z0[1] = tmp[1]; w_z0[2] = 0.f; w_z0[3] = tmp[2];
  sm3d(sload(as_seq1 + 0), sload(as_seq1 + 1), sload(as_seq1 + 2), 1.f / 3.f, tmp);
  w_t1[0] = tmp[0]; w_t1[1] = tmp[1]; w_t1[2] = tmp[2]; w_t1[3] = 0.f;
  sm3d(sload(as_last_res1 + 0), sload(as_last_res1 + 1), sload(as_last_res1 + 2),
       1.f / 3.f, tmp);
  w_z1[0] = tmp[0]; w_z1[1] = tmp[1]; w_z1[2] = 0.f; w_z1[3] = tmp[2];

  int nA[4], baseA[4];
  bool fits = true;
#pragma unroll
  for (int a = 0; a < 4; a++) {
    int key = a * NB + b;
    int base = key_base(off2, key);
    int ntot = key_end(off2, key) - base;
    int rs, re;
    if (ntot <= CAP) {
      int mid = __builtin_amdgcn_readfirstlane(rofftab[(size_t)key * RB + RBH]);
      rs = bh ? mid : 0;
      re = bh ? ntot : mid;
    } else {  // pack left region unsorted: both halves slow-scan the whole region
      rs = 0; re = ntot; fits = false;
    }
    baseA[a] = base + rs;
    nA[a] = re - rs;
    if (nA[a] > CAPH) fits = false;
  }
  int rowbase = b * RB + bh * RBH + wv * 4;
  if (fits) {
#pragma unroll
    for (int a = 0; a < 4; a++) {
      int n = nA[a], base = baseA[a];
      for (int i = t; i < n; i += 256) {
        int2 p = epk[base + i];
        se[a * CAPH + i] = make_int2((p.x & 0x1FFFF) << 8, p.y);
      }
    }
    if (t < 4 * (RBH + 1)) {
      int a = t / (RBH + 1), rr = t % (RBH + 1);
      int key = a * NB + b;
      int kb = off2[(size_t)key << 6];
      int ke = (key + 1 < NKEY) ? off2[(size_t)(key + 1) << 6] : (int)ME;
      int rs0 = bh ? rofftab[(size_t)key * RB + RBH] : 0;
      int ar = bh * RBH + rr;
      int v = (ar < RB) ? rofftab[(size_t)key * RB + ar] : (ke - kb);
      ro[a][rr] = v - rs0;
    }
    __syncthreads();
    const unsigned char* xb = (const unsigned char*)xpb;
    unsigned lane4 = (unsigned)lane << 2;
    // finish a segment 4-deep + scalar tail, both bf16 halves
    auto tl2 = [&](const int2* sp, int i, int e, float& s0, float& s1,
                   float& t0, float& t1) {
      for (; i + 3 < e; i += 4) {
        int2 p0 = sp[i], p1 = sp[i + 1], p2 = sp[i + 2], p3 = sp[i + 3];
        unsigned g0 = *(const unsigned int*)(xb + ((unsigned)p0.x + lane4));
        unsigned g1 = *(const unsigned int*)(xb + ((unsigned)p1.x + lane4));
        unsigned g2 = *(const unsigned int*)(xb + ((unsigned)p2.x + lane4));
        unsigned g3 = *(const unsigned int*)(xb + ((unsigned)p3.x + lane4));
        float v0 = __int_as_float(p0.y), v1 = __int_as_float(p1.y);
        float v2 = __int_as_float(p2.y), v3 = __int_as_float(p3.y);
        s0 = fmaf(v0, bf_lo(g0), s0); t0 = fmaf(v0, bf_hi(g0), t0);
        s1 = fmaf(v1, bf_lo(g1), s1); t1 = fmaf(v1, bf_hi(g1), t1);
        s0 = fmaf(v2, bf_lo(g2), s0); t0 = fmaf(v2, bf_hi(g2), t0);
        s1 = fmaf(v3, bf_lo(g3), s1); t1 = fmaf(v3, bf_hi(g3), t1);
      }
      for (; i < e; i++) {
        int2 p = sp[i];
        unsigned g = *(const unsigned int*)(xb + ((unsigned)p.x + lane4));
        float v = __int_as_float(p.y);
        s0 = fmaf(v, bf_lo(g), s0); t0 = fmaf(v, bf_hi(g), t0);
      }
    };
    for (int r8 = 0; r8 < 4; r8++) {
      int r = wv * 4 + r8;
      float vs1 = 0.f, vt1 = 0.f, vres = 0.f, vz0 = 0.f, vz1 = 0.f;
#pragma unroll
      for (int ap = 0; ap < 2; ap++) {
        int aA = ap << 1, aB = aA | 1;
        const int2* spA = se + aA * CAPH;
        const int2* spB = se + aB * CAPH;
        int iA = ro[aA][r], eA = ro[aA][r + 1];
        int iB = ro[aB][r], eB = ro[aB][r + 1];
        float sA0 = 0.f, sA1 = 0.f, tA0 = 0.f, tA1 = 0.f;
        float sB0 = 0.f, sB1 = 0.f, tB0 = 0.f, tB1 = 0.f;
        int dA = eA - iA, dB = eB - iB;
        int m = (dA < dB ? dA : dB) >> 2;   // joint 4+4: 8 gathers in flight
        for (int k = 0; k < m; k++) {
          int2 a0 = spA[iA], a1 = spA[iA + 1], a2 = spA[iA + 2], a3 = spA[iA + 3];
          int2 b0 = spB[iB], b1 = spB[iB + 1], b2 = spB[iB + 2], b3 = spB[iB + 3];
          unsigned gA0 = *(const unsigned int*)(xb + ((unsigned)a0.x + lane4));
          unsigned gA1 = *(const unsigned int*)(xb + ((unsigned)a1.x + lane4));
          unsigned gA2 = *(const unsigned int*)(xb + ((unsigned)a2.x + lane4));
          unsigned gA3 = *(const unsigned int*)(xb + ((unsigned)a3.x + lane4));
          unsigned gB0 = *(const unsigned int*)(xb + ((unsigned)b0.x + lane4));
          unsigned gB1 = *(const unsigned int*)(xb + ((unsigned)b1.x + lane4));
          unsigned gB2 = *(const unsigned int*)(xb + ((unsigned)b2.x + lane4));
          unsigned gB3 = *(const unsigned int*)(xb + ((unsigned)b3.x + lane4));
          float vA0 = __int_as_float(a0.y), vA1 = __int_as_float(a1.y);
          float vA2 = __int_as_float(a2.y), vA3 = __int_as_float(a3.y);
          float vB0 = __int_as_float(b0.y), vB1 = __int_as_float(b1.y);
          float vB2 = __int_as_float(b2.y), vB3 = __int_as_float(b3.y);
          sA0 = fmaf(vA0, bf_lo(gA0), sA0); tA0 = fmaf(vA0, bf_hi(gA0), tA0);
          sA1 = fmaf(vA1, bf_lo(gA1), sA1); tA1 = fmaf(vA1, bf_hi(gA1), tA1);
          sA0 = fmaf(vA2, bf_lo(gA2), sA0); tA0 = fmaf(vA2, bf_hi(gA2), tA0);
          sA1 = fmaf(vA3, bf_lo(gA3), sA1); tA1 = fmaf(vA3, bf_hi(gA3), tA1);
          sB0 = fmaf(vB0, bf_lo(gB0), sB0); tB0 = fmaf(vB0, bf_hi(gB0), tB0);
          sB1 = fmaf(vB1, bf_lo(gB1), sB1); tB1 = fmaf(vB1, bf_hi(gB1), tB1);
          sB0 = fmaf(vB2, bf_lo(gB2), sB0); tB0 = fmaf(vB2, bf_hi(gB2), tB0);
          sB1 = fmaf(vB3, bf_lo(gB3), sB1); tB1 = fmaf(vB3, bf_hi(gB3), tB1);
          iA += 4; iB += 4;
        }
        tl2(spA, iA, eA, sA0, sA1, tA0, tA1);
        tl2(spB, iB, eB, sB0, sB1, tB0, tB1);
        float sA = sA0 + sA1, tA = tA0 + tA1;
        float sB = sB0 + sB1, tB = tB0 + tB1;
        vs1  = fmaf(w_s1[aA], sA, fmaf(w_s1[aB], sB, vs1));
        vres = fmaf(w_res[aA], sA, fmaf(w_res[aB], sB, vres));
        vz0  = fmaf(w_z0[aA], sA, fmaf(w_z0[aB], sB, vz0));
        vt1  = fmaf(w_t1[aA], tA, fmaf(w_t1[aB], tB, vt1));
        vz1  = fmaf(w_z1[aA], tA, fmaf(w_z1[aB], tB, vz1));
      }
      size_t o = (size_t)(rowbase + r8) * 64 + lane;
      spb_s[o] = bf1(vs1);
      spb_t[o] = bf1(vt1);
      cres[o] = vres;
      cz0[o] = vz0;
      cz1[o] = vz1;
    }
  } else {
    // slow scan (never expected): absolute-row match
    float as1[4], at1[4], ares[4], az0[4], az1[4];
#pragma unroll
    for (int r = 0; r < 4; r++) { as1[r] = 0.f; at1[r] = 0.f; ares[r] = 0.f; az0[r] = 0.f; az1[r] = 0.f; }
    for (int a = 0; a < 4; a++) {
      int base = baseA[a], n = nA[a];
      for (int i = 0; i < n; i++) {
        int2 p = epk[base + i];
        int lr = p.x >> 17, c = p.x & 0x1FFFF;
        float v = __int_as_float(p.y);
        unsigned int g = xpb[(size_t)c * 64 + lane];
        float gs = v * bf_lo(g), gt = v * bf_hi(g);
#pragma unroll
        for (int r8 = 0; r8 < 4; r8++) {
          if (lr == bh * RBH + wv * 4 + r8) {
            as1[r8]  = fmaf(w_s1[a], gs, as1[r8]);
            ares[r8] = fmaf(w_res[a], gs, ares[r8]);
            az0[r8]  = fmaf(w_z0[a], gs, az0[r8]);
            at1[r8]  = fmaf(w_t1[a], gt, at1[r8]);
            az1[r8]  = fmaf(w_z1[a], gt, az1[r8]);
          }
        }
      }
    }
#pragma unroll
    for (int r8 = 0; r8 < 4; r8++) {
      size_t o = (size_t)(rowbase + r8) * 64 + lane;
      spb_s[o] = bf1(as1[r8]);
      spb_t[o] = bf1(at1[r8]);
      cres[o] = ares[r8];
      cz0[o] = az0[r8];
      cz1[o] = az1[r8];
    }
  }
}

// stage 2: gather split s1/t1 planes; t-plane only touched for adjs 0,1.
// read cres, emit s2b; accumulate cz0, cz1
__global__ __launch_bounds__(256, 8) void st2_kernel(
    const int* __restrict__ off2,
    const int* __restrict__ rofftab, const int2* __restrict__ epk,
    const unsigned short* __restrict__ spb_s, const unsigned short* __restrict__ spb_t,
    const float* __restrict__ as_seq0, const float* __restrict__ as_last_res0,
    const float* __restrict__ as_last_seq1,
    const float* __restrict__ cres, unsigned short* __restrict__ s2b,
    float* __restrict__ cz0, float* __restrict__ cz1) {
  __shared__ int2 se[4 * CAPH];   // .x = byte offset (col<<7), .y = val bits
  __shared__ int ro[4][RBH + 1];
  int bb = blockIdx.x;
  int b = bb >> 1, bh = bb & 1;
  int t = threadIdx.x, wv = t >> 6, lane = t & 63;
  float w_seq[4], w_z0[4], w_z1[4], tmp[4];
  sm3d(sload(as_seq0 + 3), sload(as_seq0 + 4), sload(as_seq0 + 5), 1.f / 3.f, tmp);
  w_seq[0] = tmp[0]; w_seq[1] = tmp[1]; w_seq[2] = tmp[2]; w_seq[3] = 0.f;
  sm3d(sload(as_last_res0 + 3), sload(as_last_res0 + 4), sload(as_last_res0 + 5),
       1.f / 3.f, tmp);
  w_z0[0] = tmp[0]; w_z0[1] = tmp[1]; w_z0[2] = 0.f; w_z0[3] = tmp[2];
  sm2d(sload(as_last_seq1 + 0), sload(as_last_seq1 + 1), 0.5f, tmp);
  w_z1[0] = tmp[0]; w_z1[1] = tmp[1]; w_z1[2] = 0.f; w_z1[3] = 0.f;

  int nA[4], baseA[4];
  bool fits = true;
#pragma unroll
  for (int a = 0; a < 4; a++) {
    int key = a * NB + b;
    int base = key_base(off2, key);
    int ntot = key_end(off2, key) - base;
    int rs, re;
    if (ntot <= CAP) {
      int mid = __builtin_amdgcn_readfirstlane(rofftab[(size_t)key * RB + RBH]);
      rs = bh ? mid : 0;
      re = bh ? ntot : mid;
    } else {
      rs = 0; re = ntot; fits = false;
    }
    baseA[a] = base + rs;
    nA[a] = re - rs;
    if (nA[a] > CAPH) fits = false;
  }
  int rowbase = b * RB + bh * RBH + wv * 4;
  if (fits) {
#pragma unroll
    for (int a = 0; a < 4; a++) {
      int n = nA[a], base = baseA[a];
      for (int i = t; i < n; i += 256) {
        int2 p = epk[base + i];
        se[a * CAPH + i] = make_int2((p.x & 0x1FFFF) << 7, p.y);
      }
    }
    if (t < 4 * (RBH + 1)) {
      int a = t / (RBH + 1), rr = t % (RBH + 1);
      int key = a * NB + b;
      int kb = off2[(size_t)key << 6];
      int ke = (key + 1 < NKEY) ? off2[(size_t)(key + 1) << 6] : (int)ME;
      int rs0 = bh ? rofftab[(size_t)key * RB + RBH] : 0;
      int ar = bh * RBH + rr;
      int v = (ar < RB) ? rofftab[(size_t)key * RB + ar] : (ke - kb);
      ro[a][rr] = v - rs0;
    }
    __syncthreads();
    const unsigned char* sbs = (const unsigned char*)spb_s;
    const unsigned char* sbt = (const unsigned char*)spb_t;
    unsigned lane2 = (unsigned)lane << 1;
    // both planes (adjs 0,1)
    auto tl2 = [&](const int2* sp, int i, int e, float& s0, float& s1,
                   float& t0, float& t1) {
      for (; i + 3 < e; i += 4) {
        int2 p0 = sp[i], p1 = sp[i + 1], p2 = sp[i + 2], p3 = sp[i + 3];
        float gs0 = bf_s(*(const unsigned short*)(sbs + ((unsigned)p0.x + lane2)));
        float gt0 = bf_s(*(const unsigned short*)(sbt + ((unsigned)p0.x + lane2)));
        float gs1 = bf_s(*(const unsigned short*)(sbs + ((unsigned)p1.x + lane2)));
        float gt1 = bf_s(*(const unsigned short*)(sbt + ((unsigned)p1.x + lane2)));
        float gs2 = bf_s(*(const unsigned short*)(sbs + ((unsigned)p2.x + lane2)));
        float gt2 = bf_s(*(const unsigned short*)(sbt + ((unsigned)p2.x + lane2)));
        float gs3 = bf_s(*(const unsigned short*)(sbs + ((unsigned)p3.x + lane2)));
        float gt3 = bf_s(*(const unsigned short*)(sbt + ((unsigned)p3.x + lane2)));
        float v0 = __int_as_float(p0.y), v1 = __int_as_float(p1.y);
        float v2 = __int_as_float(p2.y), v3 = __int_as_float(p3.y);
        s0 = fmaf(v0, gs0, s0); t0 = fmaf(v0, gt0, t0);
        s1 = fmaf(v1, gs1, s1); t1 = fmaf(v1, gt1, t1);
        s0 = fmaf(v2, gs2, s0); t0 = fmaf(v2, gt2, t0);
        s1 = fmaf(v3, gs3, s1); t1 = fmaf(v3, gt3, t1);
      }
      for (; i < e; i++) {
        int2 p = sp[i];
        float gs = bf_s(*(const unsigned short*)(sbs + ((unsigned)p.x + lane2)));
        float gt = bf_s(*(const unsigned short*)(sbt + ((unsigned)p.x + lane2)));
        float v = __int_as_float(p.y);
        s0 = fmaf(v, gs, s0); t0 = fmaf(v, gt, t0);
      }
    };
    // s-plane only (adjs 2,3: t-weights are structurally zero — half the bytes)
    auto tl1 = [&](const int2* sp, int i, int e, float& s0, float& s1) {
      for (; i + 3 < e; i += 4) {
        int2 p0 = sp[i], p1 = sp[i + 1], p2 = sp[i + 2], p3 = sp[i + 3];
        float g0 = bf_s(*(const unsigned short*)(sbs + ((unsigned)p0.x + lane2)));
        float g1 = bf_s(*(const unsigned short*)(sbs + ((unsigned)p1.x + lane2)));
        float g2 = bf_s(*(const unsigned short*)(sbs + ((unsigned)p2.x + lane2)));
        float g3 = bf_s(*(const unsigned short*)(sbs + ((unsigned)p3.x + lane2)));
        s0 = fmaf(__int_as_float(p0.y), g0, s0);
        s1 = fmaf(__int_as_float(p1.y), g1, s1);
        s0 = fmaf(__int_as_float(p2.y), g2, s0);
        s1 = fmaf(__int_as_float(p3.y), g3, s1);
      }
      for (; i < e; i++) {
        int2 p = sp[i];
        float g = bf_s(*(const unsigned short*)(sbs + ((unsigned)p.x + lane2)));
        s0 = fmaf(__int_as_float(p.y), g, s0);
      }
    };
    for (int r8 = 0; r8 < 4; r8++) {
      int r = wv * 4 + r8;
      float vres = 0.f, vz0 = 0.f, vz1 = 0.f;
      {  // pair (0,1): both planes live
        const int2* spA = se;
        const int2* spB = se + CAPH;
        int iA = ro[0][r], eA = ro[0][r + 1];
        int iB = ro[1][r], eB = ro[1][r + 1];
        float sA0 = 0.f, sA1 = 0.f, tA0 = 0.f, tA1 = 0.f;
        float sB0 = 0.f, sB1 = 0.f, tB0 = 0.f, tB1 = 0.f;
        int dA = eA - iA, dB = eB - iB;
        int m = (dA < dB ? dA : dB) >> 2;
        for (int k = 0; k < m; k++) {
          int2 a0 = spA[iA], a1 = spA[iA + 1], a2 = spA[iA + 2], a3 = spA[iA + 3];
          int2 b0 = spB[iB], b1 = spB[iB + 1], b2 = spB[iB + 2], b3 = spB[iB + 3];
          float gsA0 = bf_s(*(const unsigned short*)(sbs + ((unsigned)a0.x + lane2)));
          float gtA0 = bf_s(*(const unsigned short*)(sbt + ((unsigned)a0.x + lane2)));
          float gsA1 = bf_s(*(const unsigned short*)(sbs + ((unsigned)a1.x + lane2)));
          float gtA1 = bf_s(*(const unsigned short*)(sbt + ((unsigned)a1.x + lane2)));
          float gsA2 = bf_s(*(const unsigned short*)(sbs + ((unsigned)a2.x + lane2)));
          float gtA2 = bf_s(*(const unsigned short*)(sbt + ((unsigned)a2.x + lane2)));
          float gsA3 = bf_s(*(const unsigned short*)(sbs + ((unsigned)a3.x + lane2)));
          float gtA3 = bf_s(*(const unsigned short*)(sbt + ((unsigned)a3.x + lane2)));
          float gsB0 = bf_s(*(const unsigned short*)(sbs + ((unsigned)b0.x + lane2)));
          float gtB0 = bf_s(*(const unsigned short*)(sbt + ((unsigned)b0.x + lane2)));
          float gsB1 = bf_s(*(const unsigned short*)(sbs + ((unsigned)b1.x + lane2)));
          float gtB1 = bf_s(*(const unsigned short*)(sbt + ((unsigned)b1.x + lane2)));
          float gsB2 = bf_s(*(const unsigned short*)(sbs + ((unsigned)b2.x + lane2)));
          float gtB2 = bf_s(*(const unsigned short*)(sbt + ((unsigned)b2.x + lane2)));
          float gsB3 = bf_s(*(const unsigned short*)(sbs + ((unsigned)b3.x + lane2)));
          float gtB3 = bf_s(*(const unsigned short*)(sbt + ((unsigned)b3.x + lane2)));
          float vA0 = __int_as_float(a0.y), vA1 = __int_as_float(a1.y);
          float vA2 = __int_as_float(a2.y), vA3 = __int_as_float(a3.y);
          float vB0 = __int_as_float(b0.y), vB1 = __int_as_float(b1.y);
          float vB2 = __int_as_float(b2.y), vB3 = __int_as_float(b3.y);
          sA0 = fmaf(vA0, gsA0, sA0); tA0 = fmaf(vA0, gtA0, tA0);
          sA1 = fmaf(vA1, gsA1, sA1); tA1 = fmaf(vA1, gtA1, tA1);
          sA0 = fmaf(vA2, gsA2, sA0); tA0 = fmaf(vA2, gtA2, tA0);
          sA1 = fmaf(vA3, gsA3, sA1); tA1 = fmaf(vA3, gtA3, tA1);
          sB0 = fmaf(vB0, gsB0, sB0); tB0 = fmaf(vB0, gtB0, tB0);
          sB1 = fmaf(vB1, gsB1, sB1); tB1 = fmaf(vB1, gtB1, tB1);
          sB0 = fmaf(vB2, gsB2, sB0); tB0 = fmaf(vB2, gtB2, tB0);
          sB1 = fmaf(vB3, gsB3, sB1); tB1 = fmaf(vB3, gtB3, tB1);
          iA += 4; iB += 4;
        }
        tl2(spA, iA, eA, sA0, sA1, tA0, tA1);
        tl2(spB, iB, eB, sB0, sB1, tB0, tB1);
        float sA = sA0 + sA1, tA = tA0 + tA1;
        float sB = sB0 + sB1, tB = tB0 + tB1;
        vres = fmaf(w_seq[0], sA, fmaf(w_seq[1], sB, vres));
        vz0  = fmaf(w_z0[0], sA, fmaf(w_z0[1], sB, vz0));
        vz1  = fmaf(w_z1[0], tA, fmaf(w_z1[1], tB, vz1));
      }
      {  // pair (2,3): s-plane only
        const int2* spA = se + 2 * CAPH;
        const int2* spB = se + 3 * CAPH;
        int iA = ro[2][r], eA = ro[2][r + 1];
        int iB = ro[3][r], eB = ro[3][r + 1];
        float sA0 = 0.f, sA1 = 0.f, sB0 = 0.f, sB1 = 0.f;
        int dA = eA - iA, dB = eB - iB;
        int m = (dA < dB ? dA : dB) >> 2;
        for (int k = 0; k < m; k++) {
          int2 a0 = spA[iA], a1 = spA[iA + 1], a2 = spA[iA + 2], a3 = spA[iA + 3];
          int2 b0 = spB[iB], b1 = spB[iB + 1], b2 = spB[iB + 2], b3 = spB[iB + 3];
          float gA0 = bf_s(*(const unsigned short*)(sbs + ((unsigned)a0.x + lane2)));
          float gA1 = bf_s(*(const unsigned short*)(sbs + ((unsigned)a1.x + lane2)));
          float gA2 = bf_s(*(const unsigned short*)(sbs + ((unsigned)a2.x + lane2)));
          float gA3 = bf_s(*(const unsigned short*)(sbs + ((unsigned)a3.x + lane2)));
          float gB0 = bf_s(*(const unsigned short*)(sbs + ((unsigned)b0.x + lane2)));
          float gB1 = bf_s(*(const unsigned short*)(sbs + ((unsigned)b1.x + lane2)));
          float gB2 = bf_s(*(const unsigned short*)(sbs + ((unsigned)b2.x + lane2)));
          float gB3 = bf_s(*(const unsigned short*)(sbs + ((unsigned)b3.x + lane2)));
          sA0 = fmaf(__int_as_float(a0.y), gA0, sA0);
          sA1 = fmaf(__int_as_float(a1.y), gA1, sA1);
          sA0 = fmaf(__int_as_float(a2.y), gA2, sA0);
          sA1 = fmaf(__int_as_float(a3.y), gA3, sA1);
          sB0 = fmaf(__int_as_float(b0.y), gB0, sB0);
          sB1 = fmaf(__int_as_float(b1.y), gB1, sB1);
          sB0 = fmaf(__int_as_float(b2.y), gB2, sB0);
          sB1 = fmaf(__int_as_float(b3.y), gB3, sB1);
          iA += 4; iB += 4;
        }
        tl1(spA, iA, eA, sA0, sA1);
        tl1(spB, iB, eB, sB0, sB1);
        float sA = sA0 + sA1, sB = sB0 + sB1;
        vres = fmaf(w_seq[2], sA, fmaf(w_seq[3], sB, vres));
        vz0  = fmaf(w_z0[2], sA, fmaf(w_z0[3], sB, vz0));
      }
      size_t o = (size_t)(rowbase + r8) * 64 + lane;
      float s2v = cres[o] + vres;   // cres is dead after this kernel: no store-back
      s2b[o] = bf1(s2v);
      cz0[o] += vz0;
      cz1[o] += vz1;
    }
  } else {
    float dres[4], dz0[4], dz1[4];
#pragma unroll
    for (int r = 0; r < 4; r++) { dres[r] = 0.f; dz0[r] = 0.f; dz1[r] = 0.f; }
    for (int a = 0; a < 4; a++) {
      int base = baseA[a], n = nA[a];
      for (int i = 0; i < n; i++) {
        int2 p = epk[base + i];
        int lr = p.x >> 17, c = p.x & 0x1FFFF;
        float v = __int_as_float(p.y);
        float gs = v * bf_s(spb_s[(size_t)c * 64 + lane]);
        float gt = v * bf_s(spb_t[(size_t)c * 64 + lane]);
#pragma unroll
        for (int r8 = 0; r8 < 4; r8++) {
          if (lr == bh * RBH + wv * 4 + r8) {
            dres[r8] = fmaf(w_seq[a], gs, dres[r8]);
            dz0[r8]  = fmaf(w_z0[a], gs, dz0[r8]);
            dz1[r8]  = fmaf(w_z1[a], gt, dz1[r8]);
          }
        }
      }
    }
#pragma unroll
    for (int r8 = 0; r8 < 4; r8++) {
      size_t o = (size_t)(rowbase + r8) * 64 + lane;
      float s2v = cres[o] + dres[r8];
      s2b[o] = bf1(s2v);
      cz0[o] += dz0[r8];
      cz1[o] += dz1[r8];
    }
  }
}

// stage 3 + final fused: gather s2b (adjs 0,1), z0 = cz0 + dz kept in registers;
// epilogue de-shuffled with NAMED SCALAR accumulators (no register arrays across
// non-unrolled loops — avoids the scratch-spill cliff seen in R7).
__global__ __launch_bounds__(256, 8) void st3f_kernel(
    const int* __restrict__ off2,
    const int* __restrict__ rofftab, const int2* __restrict__ epk,
    const unsigned short* __restrict__ s2b, const float* __restrict__ as_last_seq0,
    const float* __restrict__ cz0, const float* __restrict__ cz1,
    const float* __restrict__ attn1_W, const float* __restrict__ attn1_b,
    const float* __restrict__ attn2_W, const float* __restrict__ attn2_b,
    const float* __restrict__ cls_W, const float* __restrict__ cls_b,
    float* __restrict__ out) {
  __shared__ int2 se[2 * CAPH];   // gather: (byte off, val); epilogue: reused as g-store
  __shared__ int ro[2][RBH + 1];
  __shared__ float2 psh[4][4];    // per wave, per row: {p0, p1}
  int bb = blockIdx.x;
  int b = bb >> 1, bh = bb & 1;
  int t = threadIdx.x, wv = t >> 6, lane = t & 63;
  float wA[2];
  sm2d(sload(as_last_seq0 + 0), sload(as_last_seq0 + 1), 0.5f, wA);
  float wA0 = wA[0], wA1 = wA[1];
  int nA[2], baseA[2];
  bool fits = true;   // block-uniform (derived via readfirstlane)
#pragma unroll
  for (int a = 0; a < 2; a++) {
    int key = a * NB + b;
    int base = key_base(off2, key);
    int ntot = key_end(off2, key) - base;
    int rs, re;
    if (ntot <= CAP) {
      int mid = __builtin_amdgcn_readfirstlane(rofftab[(size_t)key * RB + RBH]);
      rs = bh ? mid : 0;
      re = bh ? ntot : mid;
    } else {
      rs = 0; re = ntot; fits = false;
    }
    baseA[a] = base + rs;
    nA[a] = re - rs;
    if (nA[a] > CAPH) fits = false;
  }
  int rowbase = b * RB + bh * RBH + wv * 4;
  float dz0r = 0.f, dz1r = 0.f, dz2r = 0.f, dz3r = 0.f;
  if (fits) {
#pragma unroll
    for (int a = 0; a < 2; a++) {
      int n = nA[a], base = baseA[a];
      for (int i = t; i < n; i += 256) {
        int2 p = epk[base + i];
        se[a * CAPH + i] = make_int2((p.x & 0x1FFFF) << 7, p.y);
      }
    }
    if (t < 2 * (RBH + 1)) {
      int a = t / (RBH + 1), rr = t % (RBH + 1);
      int key = a * NB + b;
      int kb = off2[(size_t)key << 6];
      int ke = (key + 1 < NKEY) ? off2[(size_t)(key + 1) << 6] : (int)ME;
      int rs0 = bh ? rofftab[(size_t)key * RB + RBH] : 0;
      int ar = bh * RBH + rr;
      int v = (ar < RB) ? rofftab[(size_t)key * RB + ar] : (ke - kb);
      ro[a][rr] = v - rs0;
    }
    __syncthreads();
    const unsigned char* sb = (const unsigned char*)s2b;
    unsigned lane2 = (unsigned)lane << 1;
    auto tlu = [&](const int2* sp, int i, int e, float& s0, float& s1) {
      for (; i + 3 < e; i += 4) {
        int2 p0 = sp[i], p1 = sp[i + 1], p2 = sp[i + 2], p3 = sp[i + 3];
        float g0 = bf_s(*(const unsigned short*)(sb + ((unsigned)p0.x + lane2)));
        float g1 = bf_s(*(const unsigned short*)(sb + ((unsigned)p1.x + lane2)));
        float g2 = bf_s(*(const unsigned short*)(sb + ((unsigned)p2.x + lane2)));
        float g3 = bf_s(*(const unsigned short*)(sb + ((unsigned)p3.x + lane2)));
        s0 = fmaf(__int_as_float(p0.y), g0, s0);
        s1 = fmaf(__int_as_float(p1.y), g1, s1);
        s0 = fmaf(__int_as_float(p2.y), g2, s0);
        s1 = fmaf(__int_as_float(p3.y), g3, s1);
      }
      for (; i < e; i++) {
        int2 p = sp[i];
        float g = bf_s(*(const unsigned short*)(sb + ((unsigned)p.x + lane2)));
        s0 = fmaf(__int_as_float(p.y), g, s0);
      }
    };
    auto row_gather = [&](int r) -> float {
      const int2* spA = se;
      const int2* spB = se + CAPH;
      int iA = ro[0][r], eA = ro[0][r + 1];
      int iB = ro[1][r], eB = ro[1][r + 1];
      float sA0 = 0.f, sA1 = 0.f, sB0 = 0.f, sB1 = 0.f;
      int dA = eA - iA, dB = eB - iB;
      int m = (dA < dB ? dA : dB) >> 2;
      for (int k = 0; k < m; k++) {
        int2 a0 = spA[iA], a1 = spA[iA + 1], a2 = spA[iA + 2], a3 = spA[iA + 3];
        int2 b0 = spB[iB], b1 = spB[iB + 1], b2 = spB[iB + 2], b3 = spB[iB + 3];
        float gA0 = bf_s(*(const unsigned short*)(sb + ((unsigned)a0.x + lane2)));
        float gA1 = bf_s(*(const unsigned short*)(sb + ((unsigned)a1.x + lane2)));
        float gA2 = bf_s(*(const unsigned short*)(sb + ((unsigned)a2.x + lane2)));
        float gA3 = bf_s(*(const unsigned short*)(sb + ((unsigned)a3.x + lane2)));
        float gB0 = bf_s(*(const unsigned short*)(sb + ((unsigned)b0.x + lane2)));
        float gB1 = bf_s(*(const unsigned short*)(sb + ((unsigned)b1.x + lane2)));
        float gB2 = bf_s(*(const unsigned short*)(sb + ((unsigned)b2.x + lane2)));
        float gB3 = bf_s(*(const unsigned short*)(sb + ((unsigned)b3.x + lane2)));
        sA0 = fmaf(__int_as_float(a0.y), gA0, sA0);
        sA1 = fmaf(__int_as_float(a1.y), gA1, sA1);
        sA0 = fmaf(__int_as_float(a2.y), gA2, sA0);
        sA1 = fmaf(__int_as_float(a3.y), gA3, sA1);
        sB0 = fmaf(__int_as_float(b0.y), gB0, sB0);
        sB1 = fmaf(__int_as_float(b1.y), gB1, sB1);
        sB0 = fmaf(__int_as_float(b2.y), gB2, sB0);
        sB1 = fmaf(__int_as_float(b3.y), gB3, sB1);
        iA += 4; iB += 4;
      }
      tlu(spA, iA, eA, sA0, sA1);
      tlu(spB, iB, eB, sB0, sB1);
      return fmaf(wA0, sA0 + sA1, wA1 * (sB0 + sB1));
    };
    dz0r = row_gather(wv * 4 + 0);
    dz1r = row_gather(wv * 4 + 1);
    dz2r = row_gather(wv * 4 + 2);
    dz3r = row_gather(wv * 4 + 3);
  } else {
    for (int a = 0; a < 2; a++) {
      int base = baseA[a], n = nA[a];
      float wa = a ? wA1 : wA0;
      for (int i = 0; i < n; i++) {
        int2 p = epk[base + i];
        int lr = p.x >> 17, c = p.x & 0x1FFFF;
        float v = __int_as_float(p.y);
        float gs = v * bf_s(s2b[(size_t)c * 64 + lane]);
        int lr0 = bh * RBH + wv * 4;
        if (lr == lr0 + 0) dz0r = fmaf(wa, gs, dz0r);
        if (lr == lr0 + 1) dz1r = fmaf(wa, gs, dz1r);
        if (lr == lr0 + 2) dz2r = fmaf(wa, gs, dz2r);
        if (lr == lr0 + 3) dz3r = fmaf(wa, gs, dz3r);
      }
    }
  }

  // ---- fused epilogue (de-shuffled, scalar-only): reuse se as g-store ----
  __syncthreads();
  float2* gsh = (float2*)se;            // [4 waves][4 rows][64] float2 {g0,g1} = 8 KB
  float aw = attn2_W[lane];
  float ab = attn1_b[lane];
  float a2b = sload(attn2_b);

  // phase A: LN + gelu per row; stash {g0,g1} (1 ds_write_b64/row)
  auto ln_gelu_store = [&](float dzr, int r8) {
    size_t o = (size_t)(rowbase + r8) * 64 + lane;
    float z0 = cz0[o] + dzr;
    float z1 = cz1[o];
    float m0 = wave_bsum(z0) * (1.f / 64.f);
    float dv0 = z0 - m0;
    float var0 = wave_bsum(dv0 * dv0) * (1.f / 64.f);
    float y0 = dv0 * rsqrtf(var0 + 1e-5f);
    float g0 = 0.5f * y0 * (1.f + erff(y0 * 0.70710678118654752f));
    float m1 = wave_bsum(z1) * (1.f / 64.f);
    float dv1 = z1 - m1;
    float var1 = wave_bsum(dv1 * dv1) * (1.f / 64.f);
    float y1 = dv1 * rsqrtf(var1 + 1e-5f);
    float g1 = 0.5f * y1 * (1.f + erff(y1 * 0.70710678118654752f));
    gsh[((size_t)wv * 4 + r8) * 64 + lane] = make_float2(g0, g1);
  };
  ln_gelu_store(dz0r, 0);
  ln_gelu_store(dz1r, 1);
  ln_gelu_store(dz2r, 2);
  ln_gelu_store(dz3r, 3);

  // phase B: joint 4-row attn1 matvec via uniform-address b128 broadcast reads.
  // Named scalar accumulators only (no arrays -> no scratch). j-order matches
  // the reference shfl loop -> t accumulation bit-exact.
  float t00 = ab, t01 = ab, t02 = ab, t03 = ab;
  float u10 = ab, u11 = ab, u12 = ab, u13 = ab;
  const float4* gq = (const float4*)(gsh + (size_t)wv * 256);  // 32 float4 per row
  for (int j2 = 0; j2 < 32; j2++) {
    float w0 = attn1_W[(2 * j2) * HD + lane];
    float w1 = attn1_W[(2 * j2 + 1) * HD + lane];
    float4 ga = gq[j2];          // row 0: {g0_j, g1_j, g0_j+1, g1_j+1}
    float4 gb = gq[32 + j2];     // row 1
    float4 gc = gq[64 + j2];     // row 2
    float4 gd = gq[96 + j2];     // row 3
    t00 = fmaf(ga.x, w0, t00); u10 = fmaf(ga.y, w0, u10);
    t00 = fmaf(ga.z, w1, t00); u10 = fmaf(ga.w, w1, u10);
    t01 = fmaf(gb.x, w0, t01); u11 = fmaf(gb.y, w0, u11);
    t01 = fmaf(gb.z, w1, t01); u11 = fmaf(gb.w, w1, u11);
    t02 = fmaf(gc.x, w0, t02); u12 = fmaf(gc.y, w0, u12);
    t02 = fmaf(gc.z, w1, t02); u12 = fmaf(gc.w, w1, u12);
    t03 = fmaf(gd.x, w0, t03); u13 = fmaf(gd.y, w0, u13);
    t03 = fmaf(gd.z, w1, t03); u13 = fmaf(gd.w, w1, u13);
  }

  // phase C: per-row attention scores + softmax; stash {p0,p1} (constant row idx)
  auto scorer = [&](float tv0, float tv1, int r) {
    float tt0 = tanhf(tv0), tt1 = tanhf(tv1);
    float a0 = wave_bsum(tt0 * aw) + a2b;
    float a1 = wave_bsum(tt1 * aw) + a2b;
    float mx = fmaxf(a0, a1);
    float e0 = expf(a0 - mx), e1 = expf(a1 - mx);
    float inv = 1.f / (e0 + e1);
    if (lane == 0) psh[wv][r] = make_float2(e0 * inv, e1 * inv);
  };
  scorer(t00, u10, 0);
  scorer(t01, u11, 1);
  scorer(t02, u12, 2);
  scorer(t03, u13, 3);

  // phase D: classifier. out = p0*(g0@C) + p1*(g1@C) + b.
  // lanes 0..31: (row, class) = (lane>>3, lane&7); coalesced 128B store.
  if (lane < 32) {
    int r = lane >> 3, k = lane & 7;
    float2 pp = psh[wv][r];
    const float4* gr = (const float4*)(gsh + ((size_t)wv * 4 + r) * 64);
    float u0 = 0.f, u1 = 0.f;
    for (int j2 = 0; j2 < 32; j2++) {
      float4 gg = gr[j2];                 // {g0_j, g1_j, g0_j+1, g1_j+1}
      int j = j2 * 2;
      float c0 = cls_W[j * 8 + k];
      float c1 = cls_W[(j + 1) * 8 + k];
      u0 = fmaf(gg.x, c0, u0); u1 = fmaf(gg.y, c0, u1);
      u0 = fmaf(gg.z, c1, u0); u1 = fmaf(gg.w, c1, u1);
    }
    int n = rowbase + r;
    out[(size_t)n * 8 + k] = fmaf(pp.x, u0, pp.y * u1) + cls_b[k];
  }
}

extern "C" void kernel_launch(void* const* d_in, const int* in_sizes, int n_in,
                              void* d_out, int out_size, void* d_ws, size_t ws_size,
                              hipStream_t stream) {
  const float* node_feats   = (const float*)d_in[0];
  const int*   node_types   = (const int*)d_in[1];
  const int*   adj_rows     = (const int*)d_in[2];
  const int*   adj_cols     = (const int*)d_in[3];
  const float* adj_vals     = (const float*)d_in[4];
  const float* type_W       = (const float*)d_in[5];
  const float* type_b       = (const float*)d_in[6];
  const float* aW0          = (const float*)d_in[7];
  const float* ab0          = (const float*)d_in[8];
  const float* aW1          = (const float*)d_in[9];
  const float* ab1          = (const float*)d_in[10];
  const float* as_seq0      = (const float*)d_in[11];
  const float* as_last_seq0 = (const float*)d_in[12];
  const float* as_res0      = (const float*)d_in[13];
  const float* as_last_res0 = (const float*)d_in[14];
  const float* as_seq1      = (const float*)d_in[15];
  const float* as_last_seq1 = (const float*)d_in[16];
  const float* as_last_res1 = (const float*)d_in[17];
  const float* attn1_W      = (const float*)d_in[18];
  const float* attn1_b      = (const float*)d_in[19];
  const float* attn2_W      = (const float*)d_in[20];
  const float* attn2_b      = (const float*)d_in[21];
  const float* cls_W        = (const float*)d_in[22];
  const float* cls_b        = (const float*)d_in[23];
  float* out = (float*)d_out;
  float* ws = (float*)d_ws;

  unsigned int*   xpb   = (unsigned int*)(ws + XPB_OFF);
  unsigned short* spb_s = (unsigned short*)(ws + SPB_OFF);
  unsigned short* spb_t = (unsigned short*)(ws + SPB_OFF + NP / 2);
  float*          cres  = ws + CRES_OFF;
  float*          cz0   = ws + CZ0_OFF;
  float*          cz1   = ws + CZ1_OFF;
  unsigned short* s2b   = (unsigned short*)(ws + S2B_OFF);
  int2*           epk   = (int2*)(ws + EPK_OFF);
  int*            cnt2  = (int*)(ws + CNT2_OFF);
  int*            off2  = (int*)(ws + OFF2_OFF);
  int*            part  = (int*)(ws + PART_OFF);
  int*            roff  = (int*)(ws + ROFF_OFF);
  int*            ncnt  = (int*)(ws + NCNT_OFF);
  int*            noff  = (int*)(ws + NOFF_OFF);
  int*            nperm = (int*)(ws + NPERM_OFF);

  // node type sort + typed projection (8 same-type nodes per wave)
  nhist_kernel<<<NCH, 256, 0, stream>>>(node_types, ncnt);
  nscan_kernel<<<1, 256, 0, stream>>>(ncnt, noff);
  nscatter_kernel<<<NCH, 256, 0, stream>>>(node_types, noff, nperm);
  hid2_kernel<<<NNODES / 32, 256, 0, stream>>>(node_feats, node_types, nperm,
                                               type_W, type_b, aW0, ab0, aW1, ab1, xpb);

  // deterministic edge build: hist2 -> scan -> LDS-cursor scatter -> pack+sort
  histb2_kernel<<<dim3(CHK, 4), 256, 0, stream>>>(adj_rows, cnt2);
  scan1_kernel<<<SCAN1B, 256, 0, stream>>>(cnt2, off2, part);
  scan2_kernel<<<1, 1024, 0, stream>>>(part);
  scan3_kernel<<<SCAN1B, 256, 0, stream>>>(off2, part);
  scatterd_kernel<<<dim3(CHK, 4), 256, 0, stream>>>(adj_rows, adj_cols, adj_vals, off2, epk);
  pack_kernel<<<NKEY, 256, 0, stream>>>(off2, epk, roff);

  // SpMM stages (arch-weight softmaxes computed inline; keyoff inlined from off2)
  st1_kernel<<<NB * 2, 256, 0, stream>>>(off2, roff, epk, xpb,
                                         as_seq0, as_res0, as_last_res0, as_seq1,
                                         as_last_res1,
                                         spb_s, spb_t, cres, cz0, cz1);
  st2_kernel<<<NB * 2, 256, 0, stream>>>(off2, roff, epk, spb_s, spb_t,
                                         as_seq0, as_last_res0, as_last_seq1,
                                         cres, s2b, cz0, cz1);
  // stage 3 + final fused (scalar-only de-shuffled epilogue; writes logits directly)
  st3f_kernel<<<NB * 2, 256, 0, stream>>>(off2, roff, epk, s2b, as_last_seq0,
                                          cz0, cz1,
                                          attn1_W, attn1_b, attn2_W, attn2_b,
                                          cls_W, cls_b, out);
}

// Round 9
// 1248.013 us; speedup vs baseline: 2.5406x; 1.0554x over previous
//
#include <hip/hip_runtime.h>
#include <math.h>

// Problem constants (match reference file)
#define NNODES 100000
#define NEDGE  1600000
#define HD     64
#define INDIM  256

#define RB   32                 // rows per bucket
#define RBH  16                 // rows per half-bucket (stage kernels)
#define NB   3125               // NNODES / RB (exact)
#define NKEY (4 * NB)           // 12500 (a, bucket) regions
#define CAP  1024               // pack LDS capacity
#define CAPH 512                // per-adjacency stage slot per half-bucket (mean 256, +16 sigma)
#define CHK  64                 // chunks per adjacency (deterministic scatter)
#define EPC  (NEDGE / CHK)      // 25000 edges per chunk
#define NCH  100                // node chunks (type sort)
#define NPC  (NNODES / NCH)     // 1000 nodes per chunk

static constexpr size_t NP = (size_t)NNODES * HD;   // 6.4M elems per [N,H] plane
static constexpr size_t ME = (size_t)4 * NEDGE;     // 6.4M edges total
static constexpr int    M2 = NKEY * CHK;            // 800000 (key,chunk) counters
static constexpr int    SCAN1B = (M2 + 1023) / 1024;  // 782

// workspace layout (floats) — total ~200.5 MB
static constexpr size_t XPB_OFF   = 0;                   // uint bf16x2 (x0,x1): NP
static constexpr size_t SPB_OFF   = NP;                  // ushort s1 plane: NP/2 floats; ushort t1 plane: NP/2 floats
static constexpr size_t CRES_OFF  = 2 * NP;              // s2 accumulator (f32)
static constexpr size_t CZ0_OFF   = 3 * NP;              // z0 (f32)
static constexpr size_t CZ1_OFF   = 4 * NP;              // z1 (f32)
static constexpr size_t S2B_OFF   = 5 * NP;              // ushort bf16 s2: NP/2 floats
static constexpr size_t EPK_OFF   = 5 * NP + NP / 2;     // int2 (lr|col,val): 2*ME
static constexpr size_t CNT2_OFF  = EPK_OFF + 2 * ME;    // M2 ints [key][chunk]
static constexpr size_t OFF2_OFF  = CNT2_OFF + M2;       // M2 ints
static constexpr size_t PART_OFF  = OFF2_OFF + M2;       // 1024 ints
static constexpr size_t ROFF_OFF  = PART_OFF + 1024;     // NKEY*RB ints
static constexpr size_t NCNT_OFF  = ROFF_OFF + (size_t)NKEY * RB;  // 512 ints
static constexpr size_t NOFF_OFF  = NCNT_OFF + 512;      // 512 ints
static constexpr size_t NPERM_OFF = NOFF_OFF + 512;      // NNODES ints

// ---------------- helpers ----------------
__device__ __forceinline__ float wave_bsum(float v) {
#pragma unroll
  for (int m = 1; m < 64; m <<= 1) v += __shfl_xor(v, m, 64);
  return v;
}

__device__ __forceinline__ unsigned int bf2pack(float a, float b) {
  unsigned int ua = __float_as_uint(a);
  ua += 0x7FFFu + ((ua >> 16) & 1u);        // RNE
  unsigned int ub = __float_as_uint(b);
  ub += 0x7FFFu + ((ub >> 16) & 1u);
  return (ua >> 16) | (ub & 0xFFFF0000u);
}
__device__ __forceinline__ unsigned short bf1(float a) {
  unsigned int ua = __float_as_uint(a);
  ua += 0x7FFFu + ((ua >> 16) & 1u);
  return (unsigned short)(ua >> 16);
}
__device__ __forceinline__ float bf_lo(unsigned int g) { return __uint_as_float(g << 16); }
__device__ __forceinline__ float bf_hi(unsigned int g) { return __uint_as_float(g & 0xFFFF0000u); }
__device__ __forceinline__ float bf_s(unsigned short g) {
  return __uint_as_float((unsigned int)g << 16);
}
// force a uniform float load into an SGPR (keeps weight tables out of the VGPR budget)
__device__ __forceinline__ float sload(const float* p) {
  return __uint_as_float(__builtin_amdgcn_readfirstlane(__float_as_uint(*p)));
}
// softmax coefficient helpers (identical math to the old wcoef kernel)
__device__ __forceinline__ void sm3d(float a0, float a1, float a2, float sc, float* o) {
  float m = fmaxf(a0, fmaxf(a1, a2));
  float e0 = expf(a0 - m), e1 = expf(a1 - m), e2 = expf(a2 - m);
  float inv = sc / (e0 + e1 + e2);
  o[0] = e0 * inv; o[1] = e1 * inv; o[2] = e2 * inv;
}
__device__ __forceinline__ void sm2d(float a0, float a1, float sc, float* o) {
  float m = fmaxf(a0, a1);
  float e0 = expf(a0 - m), e1 = expf(a1 - m);
  float inv = sc / (e0 + e1);
  o[0] = e0 * inv; o[1] = e1 * inv;
}
__device__ __forceinline__ void sm4d(float a0, float a1, float a2, float a3, float sc, float* o) {
  float m = fmaxf(fmaxf(a0, a1), fmaxf(a2, a3));
  float e0 = expf(a0 - m), e1 = expf(a1 - m), e2 = expf(a2 - m), e3 = expf(a3 - m);
  float inv = sc / (e0 + e1 + e2 + e3);
  o[0] = e0 * inv; o[1] = e1 * inv; o[2] = e2 * inv; o[3] = e3 * inv;
}

// ================= node type sort (deterministic, chunked) =================
__global__ __launch_bounds__(256) void nhist_kernel(const int* __restrict__ types,
                                                    int* __restrict__ ncnt) {
  __shared__ int c[4];
  int ch = blockIdx.x;
  if (threadIdx.x < 4) c[threadIdx.x] = 0;
  __syncthreads();
  int base = ch * NPC;
  for (int i = base + threadIdx.x; i < base + NPC; i += 256)
    atomicAdd(&c[types[i]], 1);
  __syncthreads();
  if (threadIdx.x < 4) ncnt[threadIdx.x * NCH + ch] = c[threadIdx.x];
}

__global__ __launch_bounds__(256) void nscan_kernel(const int* __restrict__ ncnt,
                                                    int* __restrict__ noff) {
  __shared__ int sdata[256];
  int t = threadIdx.x;
  int i0 = t * 2;
  int v0 = (i0 < 4 * NCH) ? ncnt[i0] : 0;
  int v1 = (i0 + 1 < 4 * NCH) ? ncnt[i0 + 1] : 0;
  int ts = v0 + v1;
  sdata[t] = ts;
  __syncthreads();
  for (int o = 1; o < 256; o <<= 1) {
    int x = (t >= o) ? sdata[t - o] : 0;
    __syncthreads();
    sdata[t] += x;
    __syncthreads();
  }
  int excl = sdata[t] - ts;
  if (i0 < 4 * NCH) noff[i0] = excl;
  if (i0 + 1 < 4 * NCH) noff[i0 + 1] = excl + v0;
}

__global__ __launch_bounds__(256) void nscatter_kernel(const int* __restrict__ types,
                                                       const int* __restrict__ noff,
                                                       int* __restrict__ nperm) {
  __shared__ int cur[4];
  int ch = blockIdx.x;
  if (threadIdx.x < 4) cur[threadIdx.x] = noff[threadIdx.x * NCH + ch];
  __syncthreads();
  int base = ch * NPC;
  for (int i = base + threadIdx.x; i < base + NPC; i += 256) {
    int pos = atomicAdd(&cur[types[i]], 1);
    nperm[pos] = i;
  }
}

// ---------------- typed projection + both affines, type-sorted, 8 nodes/wave ----------------
__global__ __launch_bounds__(256) void hid2_kernel(
    const float* __restrict__ feats, const int* __restrict__ types,
    const int* __restrict__ nperm,
    const float* __restrict__ type_W, const float* __restrict__ type_b,
    const float* __restrict__ W0, const float* __restrict__ b0,
    const float* __restrict__ W1, const float* __restrict__ b1,
    unsigned int* __restrict__ xpb) {
  __shared__ float sh_h[4][8][64];
  int t = threadIdx.x, wv = t >> 6, lane = t & 63;
  int idx0 = blockIdx.x * 32 + wv * 8;
  int nj[8];
#pragma unroll
  for (int j = 0; j < 8; j++)
    nj[j] = __builtin_amdgcn_readfirstlane(nperm[idx0 + j]);
  int t0 = __builtin_amdgcn_readfirstlane(types[nj[0]]);
  int t7 = __builtin_amdgcn_readfirstlane(types[nj[7]]);
  float acc[8];
  if (t0 == t7) {
    const float* W = type_W + (size_t)t0 * (INDIM * HD);
    float bias = type_b[t0 * HD + lane];
#pragma unroll
    for (int j = 0; j < 8; j++) acc[j] = bias;
    for (int k = 0; k < INDIM; k += 4) {
#pragma unroll
      for (int kk = 0; kk < 4; kk++) {
        float wk = W[(k + kk) * HD + lane];
#pragma unroll
        for (int j = 0; j < 8; j++)
          acc[j] = fmaf(feats[(size_t)nj[j] * INDIM + k + kk], wk, acc[j]);
      }
    }
  } else {
    for (int j = 0; j < 8; j++) {
      int tj = __builtin_amdgcn_readfirstlane(types[nj[j]]);
      const float* W = type_W + (size_t)tj * (INDIM * HD);
      float a = type_b[tj * HD + lane];
      for (int k = 0; k < INDIM; k++)
        a = fmaf(feats[(size_t)nj[j] * INDIM + k], W[k * HD + lane], a);
      acc[j] = a;
    }
  }
#pragma unroll
  for (int j = 0; j < 8; j++) sh_h[wv][j][lane] = acc[j];
  float a0[8], a1[8];
  float bb0 = b0[lane], bb1 = b1[lane];
#pragma unroll
  for (int j = 0; j < 8; j++) { a0[j] = bb0; a1[j] = bb1; }
  for (int j2 = 0; j2 < 64; j2++) {
    float w0 = W0[j2 * HD + lane], w1 = W1[j2 * HD + lane];
#pragma unroll
    for (int j = 0; j < 8; j++) {
      float hv = sh_h[wv][j][j2];
      a0[j] = fmaf(hv, w0, a0[j]);
      a1[j] = fmaf(hv, w1, a1[j]);
    }
  }
#pragma unroll
  for (int j = 0; j < 8; j++)
    xpb[(size_t)nj[j] * HD + lane] = bf2pack(a0[j], a1[j]);
}

// ================= deterministic two-pass edge build (no global atomics) =================
// 1024-thread blocks: 16 waves/CU at 1 block/CU (was 4) — latency-bound fix
__global__ __launch_bounds__(1024) void histb2_kernel(const int* __restrict__ rows,
                                                      int* __restrict__ cnt2) {
  __shared__ int h[NB];
  int a = blockIdx.y, ch = blockIdx.x;
  for (int i = threadIdx.x; i < NB; i += 1024) h[i] = 0;
  __syncthreads();
  int base = ch * EPC;
  for (int e = base + threadIdx.x; e < base + EPC; e += 1024)
    atomicAdd(&h[rows[(size_t)a * NEDGE + e] >> 5], 1);
  __syncthreads();
  for (int b = threadIdx.x; b < NB; b += 1024)
    cnt2[((size_t)(a * NB + b) << 6) | ch] = h[b];
}

__global__ __launch_bounds__(256) void scan1_kernel(const int* __restrict__ cnt2,
                                                    int* __restrict__ off2,
                                                    int* __restrict__ part) {
  __shared__ int sdata[256];
  int t = threadIdx.x;
  int base = blockIdx.x * 1024 + t * 4;
  int v0 = (base + 0 < M2) ? cnt2[base + 0] : 0;
  int v1 = (base + 1 < M2) ? cnt2[base + 1] : 0;
  int v2 = (base + 2 < M2) ? cnt2[base + 2] : 0;
  int v3 = (base + 3 < M2) ? cnt2[base + 3] : 0;
  int tsum = v0 + v1 + v2 + v3;
  sdata[t] = tsum;
  __syncthreads();
  for (int o = 1; o < 256; o <<= 1) {
    int x = (t >= o) ? sdata[t - o] : 0;
    __syncthreads();
    sdata[t] += x;
    __syncthreads();
  }
  int excl = sdata[t] - tsum;
  if (t == 255) part[blockIdx.x] = sdata[255];
  if (base + 0 < M2) off2[base + 0] = excl;
  if (base + 1 < M2) off2[base + 1] = excl + v0;
  if (base + 2 < M2) off2[base + 2] = excl + v0 + v1;
  if (base + 3 < M2) off2[base + 3] = excl + v0 + v1 + v2;
}

__global__ __launch_bounds__(1024) void scan2_kernel(int* __restrict__ part) {
  __shared__ int sdata[1024];
  int t = threadIdx.x;
  int v = (t < SCAN1B) ? part[t] : 0;
  sdata[t] = v;
  __syncthreads();
  for (int o = 1; o < 1024; o <<= 1) {
    int x = (t >= o) ? sdata[t - o] : 0;
    __syncthreads();
    sdata[t] += x;
    __syncthreads();
  }
  if (t < SCAN1B) part[t] = sdata[t] - v;  // exclusive
}

__global__ __launch_bounds__(256) void scan3_kernel(int* __restrict__ off2,
                                                    const int* __restrict__ part) {
  int p = part[blockIdx.x];
  int t = threadIdx.x;
#pragma unroll
  for (int j = 0; j < 4; j++) {
    int i = blockIdx.x * 1024 + j * 256 + t;
    if (i < M2) off2[i] += p;
  }
}

// pass 2: deterministic scatter of packed (lr|col,val) using LDS cursors
// 1024-thread blocks for latency hiding on the scattered 8B writes
__global__ __launch_bounds__(1024) void scatterd_kernel(
    const int* __restrict__ rows, const int* __restrict__ cols, const float* __restrict__ vals,
    const int* __restrict__ off2, int2* __restrict__ epk) {
  __shared__ int cur[NB];
  int a = blockIdx.y, ch = blockIdx.x;
  for (int b = threadIdx.x; b < NB; b += 1024)
    cur[b] = off2[((size_t)(a * NB + b) << 6) | ch];
  __syncthreads();
  int base = ch * EPC;
  for (int e = base + threadIdx.x; e < base + EPC; e += 1024) {
    size_t idx = (size_t)a * NEDGE + e;
    int r = rows[idx];
    int pos = atomicAdd(&cur[r >> 5], 1);
    epk[pos] = make_int2(((r & 31) << 17) | cols[idx], __float_as_int(vals[idx]));
  }
}

// pack: per bucket, coalesced read epk region, counting-sort by local row in LDS,
// write back sorted + rofftab  (key offsets computed from off2 directly)
__global__ __launch_bounds__(256) void pack_kernel(
    const int* __restrict__ off2,
    int2* __restrict__ epk, int* __restrict__ rofftab) {
  __shared__ int smeta[CAP];
  __shared__ float sval[CAP];
  __shared__ int h[RB], hc[RB];
  int key = blockIdx.x;
  int base = off2[(size_t)key << 6];
  int kend = (key + 1 < NKEY) ? off2[(size_t)(key + 1) << 6] : (int)ME;
  int n = kend - base;
  int t = threadIdx.x, wv = t >> 6, lane = t & 63;
  if (t < RB) h[t] = 0;
  __syncthreads();
  if (n <= CAP) {
    int lm[4]; float lv[4];
    int cl = 0;
#pragma unroll
    for (int j = 0; j < 4; j++) {
      int i = t + j * 256;
      if (i < n) {
        int2 p = epk[base + i];
        lm[cl] = p.x;
        lv[cl] = __int_as_float(p.y);
        cl++;
        atomicAdd(&h[p.x >> 17], 1);
      }
    }
    __syncthreads();
    if (wv == 0) {
      int v = (lane < RB) ? h[lane] : 0;
      int incl = v;
#pragma unroll
      for (int o = 1; o < RB; o <<= 1) {
        int x = __shfl_up(incl, o, 64);
        if (lane >= o) incl += x;
      }
      if (lane < RB) {
        int excl = incl - v;
        hc[lane] = excl;
        rofftab[(size_t)key * RB + lane] = excl;
      }
    }
    __syncthreads();
    for (int j = 0; j < cl; j++) {
      int p = atomicAdd(&hc[lm[j] >> 17], 1);
      smeta[p] = lm[j];
      sval[p] = lv[j];
    }
    __syncthreads();
    for (int i = t; i < n; i += 256)
      epk[base + i] = make_int2(smeta[i], __float_as_int(sval[i]));
  }
  // n > CAP: leave unsorted; stages use slow scan path (never expected)
}

// ================= SpMM stages: half-bucket blocks, 4 rows/wave, joint-pair gathers =====

// region lookup from off2 (keyoff kernel inlined)
__device__ __forceinline__ int key_base(const int* off2, int key) {
  return __builtin_amdgcn_readfirstlane(off2[(size_t)key << 6]);
}
__device__ __forceinline__ int key_end(const int* off2, int key) {
  return (key + 1 < NKEY)
             ? __builtin_amdgcn_readfirstlane(off2[(size_t)(key + 1) << 6])
             : (int)ME;
}

// stage 1: gather xpb (bf16 x0,x1); write spb_s/spb_t (split bf16 planes), cres, cz0, cz1
__global__ __launch_bounds__(256, 8) void st1_kernel(
    const int* __restrict__ off2,
    const int* __restrict__ rofftab, const int2* __restrict__ epk,
    const unsigned int* __restrict__ xpb,
    const float* __restrict__ as_seq0, const float* __restrict__ as_res0,
    const float* __restrict__ as_last_res0, const float* __restrict__ as_seq1,
    const float* __restrict__ as_last_res1,
    unsigned short* __restrict__ spb_s, unsigned short* __restrict__ spb_t,
    float* __restrict__ cres, float* __restrict__ cz0, float* __restrict__ cz1) {
  __shared__ int2 se[4 * CAPH];     // .x = byte offset (col<<8), .y = val bits
  __shared__ int ro[4][RBH + 1];
  int bb = blockIdx.x;
  int b = bb >> 1, bh = bb & 1;
  int t = threadIdx.x, wv = t >> 6, lane = t & 63;
  // arch weights (wcoef inlined, identical math)
  float w_s1[4], w_res[4], w_z0[4], w_t1[4], w_z1[4], tmp[4];
  sm3d(sload(as_seq0 + 0), sload(as_seq0 + 1), sload(as_seq0 + 2), 1.f / 3.f, tmp);
  w_s1[0] = tmp[0]; w_s1[1] = tmp[1]; w_s1[2] = tmp[2]; w_s1[3] = 0.f;
  sm4d(sload(as_res0 + 0), sload(as_res0 + 1), sload(as_res0 + 2), sload(as_res0 + 3),
       0.25f, w_res);
  sm3d(sload(as_last_res0 + 0), sload(as_last_res0 + 1), sload(as_last_res0 + 2),
       1.f / 3.f, tmp);
  w_z0[0] = tmp[0]; w_z0[1] = tmp[1]; w_z0[2] = 0.f; w_z0[3] = tmp[2];
  sm3d(sload(as_seq1 + 0), sload(as_seq1 + 1), sload(as_seq1 + 2), 1.f / 3.f, tmp);
  w_t1[0] = tmp[0]; w_t1[1] = tmp[1]; w_t1[2] = tmp[2]; w_t1[3] = 0.f;
  sm3d(sload(as_last_res1 + 0), sload(as_last_res1 + 1), sload(as_last_res1 + 2),
       1.f / 3.f, tmp);
  w_z1[0] = tmp[0]; w_z1[1] = tmp[1]; w_z1[2] = 0.f; w_z1[3] = tmp[2];

  int nA[4], baseA[4];
  bool fits = true;
#pragma unroll
  for (int a = 0; a < 4; a++) {
    int key = a * NB + b;
    int base = key_base(off2, key);
    int ntot = key_end(off2, key) - base;
    int rs, re;
    if (ntot <= CAP) {
      int mid = __builtin_amdgcn_readfirstlane(rofftab[(size_t)key * RB + RBH]);
      rs = bh ? mid : 0;
      re = bh ? ntot : mid;
    } else {  // pack left region unsorted: both halves slow-scan the whole region
      rs = 0; re = ntot; fits = false;
    }
    baseA[a] = base + rs;
    nA[a] = re - rs;
    if (nA[a] > CAPH) fits = false;
  }
  int rowbase = b * RB + bh * RBH + wv * 4;
  if (fits) {
#pragma unroll
    for (int a = 0; a < 4; a++) {
      int n = nA[a], base = baseA[a];
      for (int i = t; i < n; i += 256) {
        int2 p = epk[base + i];
        se[a * CAPH + i] = make_int2((p.x & 0x1FFFF) << 8, p.y);
      }
    }
    if (t < 4 * (RBH + 1)) {
      int a = t / (RBH + 1), rr = t % (RBH + 1);
      int key = a * NB + b;
      int kb = off2[(size_t)key << 6];
      int ke = (key + 1 < NKEY) ? off2[(size_t)(key + 1) << 6] : (int)ME;
      int rs0 = bh ? rofftab[(size_t)key * RB + RBH] : 0;
      int ar = bh * RBH + rr;
      int v = (ar < RB) ? rofftab[(size_t)key * RB + ar] : (ke - kb);
      ro[a][rr] = v - rs0;
    }
    __syncthreads();
    const unsigned char* xb = (const unsigned char*)xpb;
    unsigned lane4 = (unsigned)lane << 2;
    // finish a segment 4-deep + scalar tail, both bf16 halves
    auto tl2 = [&](const int2* sp, int i, int e, float& s0, float& s1,
                   float& t0, float& t1) {
      for (; i + 3 < e; i += 4) {
        int2 p0 = sp[i], p1 = sp[i + 1], p2 = sp[i + 2], p3 = sp[i + 3];
        unsigned g0 = *(const unsigned int*)(xb + ((unsigned)p0.x + lane4));
        unsigned g1 = *(const unsigned int*)(xb + ((unsigned)p1.x + lane4));
        unsigned g2 = *(const unsigned int*)(xb + ((unsigned)p2.x + lane4));
        unsigned g3 = *(const unsigned int*)(xb + ((unsigned)p3.x + lane4));
        float v0 = __int_as_float(p0.y), v1 = __int_as_float(p1.y);
        float v2 = __int_as_float(p2.y), v3 = __int_as_float(p3.y);
        s0 = fmaf(v0, bf_lo(g0), s0); t0 = fmaf(v0, bf_hi(g0), t0);
        s1 = fmaf(v1, bf_lo(g1), s1); t1 = fmaf(v1, bf_hi(g1), t1);
        s0 = fmaf(v2, bf_lo(g2), s0); t0 = fmaf(v2, bf_hi(g2), t0);
        s1 = fmaf(v3, bf_lo(g3), s1); t1 = fmaf(v3, bf_hi(g3), t1);
      }
      for (; i < e; i++) {
        int2 p = sp[i];
        unsigned g = *(const unsigned int*)(xb + ((unsigned)p.x + lane4));
        float v = __int_as_float(p.y);
        s0 = fmaf(v, bf_lo(g), s0); t0 = fmaf(v, bf_hi(g), t0);
      }
    };
    for (int r8 = 0; r8 < 4; r8++) {
      int r = wv * 4 + r8;
      float vs1 = 0.f, vt1 = 0.f, vres = 0.f, vz0 = 0.f, vz1 = 0.f;
#pragma unroll
      for (int ap = 0; ap < 2; ap++) {
        int aA = ap << 1, aB = aA | 1;
        const int2* spA = se + aA * CAPH;
        const int2* spB = se + aB * CAPH;
        int iA = ro[aA][r], eA = ro[aA][r + 1];
        int iB = ro[aB][r], eB = ro[aB][r + 1];
        float sA0 = 0.f, sA1 = 0.f, tA0 = 0.f, tA1 = 0.f;
        float sB0 = 0.f, sB1 = 0.f, tB0 = 0.f, tB1 = 0.f;
        int dA = eA - iA, dB = eB - iB;
        int m = (dA < dB ? dA : dB) >> 2;   // joint 4+4: 8 gathers in flight
        for (int k = 0; k < m; k++) {
          int2 a0 = spA[iA], a1 = spA[iA + 1], a2 = spA[iA + 2], a3 = spA[iA + 3];
          int2 b0 = spB[iB], b1 = spB[iB + 1], b2 = spB[iB + 2], b3 = spB[iB + 3];
          unsigned gA0 = *(const unsigned int*)(xb + ((unsigned)a0.x + lane4));
          unsigned gA1 = *(const unsigned int*)(xb + ((unsigned)a1.x + lane4));
          unsigned gA2 = *(const unsigned int*)(xb + ((unsigned)a2.x + lane4));
          unsigned gA3 = *(const unsigned int*)(xb + ((unsigned)a3.x + lane4));
          unsigned gB0 = *(const unsigned int*)(xb + ((unsigned)b0.x + lane4));
          unsigned gB1 = *(const unsigned int*)(xb + ((unsigned)b1.x + lane4));
          unsigned gB2 = *(const unsigned int*)(xb + ((unsigned)b2.x + lane4));
          unsigned gB3 = *(const unsigned int*)(xb + ((unsigned)b3.x + lane4));
          float vA0 = __int_as_float(a0.y), vA1 = __int_as_float(a1.y);
          float vA2 = __int_as_float(a2.y), vA3 = __int_as_float(a3.y);
          float vB0 = __int_as_float(b0.y), vB1 = __int_as_float(b1.y);
          float vB2 = __int_as_float(b2.y), vB3 = __int_as_float(b3.y);
          sA0 = fmaf(vA0, bf_lo(gA0), sA0); tA0 = fmaf(vA0, bf_hi(gA0), tA0);
          sA1 = fmaf(vA1, bf_lo(gA1), sA1); tA1 = fmaf(vA1, bf_hi(gA1), tA1);
          sA0 = fmaf(vA2, bf_lo(gA2), sA0); tA0 = fmaf(vA2, bf_hi(gA2), tA0);
          sA1 = fmaf(vA3, bf_lo(gA3), sA1); tA1 = fmaf(vA3, bf_hi(gA3), tA1);
          sB0 = fmaf(vB0, bf_lo(gB0), sB0); tB0 = fmaf(vB0, bf_hi(gB0), tB0);
          sB1 = fmaf(vB1, bf_lo(gB1), sB1); tB1 = fmaf(vB1, bf_hi(gB1), tB1);
          sB0 = fmaf(vB2, bf_lo(gB2), sB0); tB0 = fmaf(vB2, bf_hi(gB2), tB0);
          sB1 = fmaf(vB3, bf_lo(gB3), sB1); tB1 = fmaf(vB3, bf_hi(gB3), tB1);
          iA += 4; iB += 4;
        }
        tl2(spA, iA, eA, sA0, sA1, tA0, tA1);
        tl2(spB, iB, eB, sB0, sB1, tB0, tB1);
        float sA = sA0 + sA1, tA = tA0 + tA1;
        float sB = sB0 + sB1, tB = tB0 + tB1;
        vs1  = fmaf(w_s1[aA], sA, fmaf(w_s1[aB], sB, vs1));
        vres = fmaf(w_res[aA], sA, fmaf(w_res[aB], sB, vres));
        vz0  = fmaf(w_z0[aA], sA, fmaf(w_z0[aB], sB, vz0));
        vt1  = fmaf(w_t1[aA], tA, fmaf(w_t1[aB], tB, vt1));
        vz1  = fmaf(w_z1[aA], tA, fmaf(w_z1[aB], tB, vz1));
      }
      size_t o = (size_t)(rowbase + r8) * 64 + lane;
      spb_s[o] = bf1(vs1);
      spb_t[o] = bf1(vt1);
      cres[o] = vres;
      cz0[o] = vz0;
      cz1[o] = vz1;
    }
  } else {
    // slow scan (never expected): absolute-row match
    float as1[4], at1[4], ares[4], az0[4], az1[4];
#pragma unroll
    for (int r = 0; r < 4; r++) { as1[r] = 0.f; at1[r] = 0.f; ares[r] = 0.f; az0[r] = 0.f; az1[r] = 0.f; }
    for (int a = 0; a < 4; a++) {
      int base = baseA[a], n = nA[a];
      for (int i = 0; i < n; i++) {
        int2 p = epk[base + i];
        int lr = p.x >> 17, c = p.x & 0x1FFFF;
        float v = __int_as_float(p.y);
        unsigned int g = xpb[(size_t)c * 64 + lane];
        float gs = v * bf_lo(g), gt = v * bf_hi(g);
#pragma unroll
        for (int r8 = 0; r8 < 4; r8++) {
          if (lr == bh * RBH + wv * 4 + r8) {
            as1[r8]  = fmaf(w_s1[a], gs, as1[r8]);
            ares[r8] = fmaf(w_res[a], gs, ares[r8]);
            az0[r8]  = fmaf(w_z0[a], gs, az0[r8]);
            at1[r8]  = fmaf(w_t1[a], gt, at1[r8]);
            az1[r8]  = fmaf(w_z1[a], gt, az1[r8]);
          }
        }
      }
    }
#pragma unroll
    for (int r8 = 0; r8 < 4; r8++) {
      size_t o = (size_t)(rowbase + r8) * 64 + lane;
      spb_s[o] = bf1(as1[r8]);
      spb_t[o] = bf1(at1[r8]);
      cres[o] = ares[r8];
      cz0[o] = az0[r8];
      cz1[o] = az1[r8];
    }
  }
}

// stage 2: gather split s1/t1 planes; t-plane only touched for adjs 0,1.
// read cres, emit s2b; accumulate cz0, cz1
__global__ __launch_bounds__(256, 8) void st2_kernel(
    const int* __restrict__ off2,
    const int* __restrict__ rofftab, const int2* __restrict__ epk,
    const unsigned short* __restrict__ spb_s, const unsigned short* __restrict__ spb_t,
    const float* __restrict__ as_seq0, const float* __restrict__ as_last_res0,
    const float* __restrict__ as_last_seq1,
    const float* __restrict__ cres, unsigned short* __restrict__ s2b,
    float* __restrict__ cz0, float* __restrict__ cz1) {
  __shared__ int2 se[4 * CAPH];   // .x = byte offset (col<<7), .y = val bits
  __shared__ int ro[4][RBH + 1];
  int bb = blockIdx.x;
  int b = bb >> 1, bh = bb & 1;
  int t = threadIdx.x, wv = t >> 6, lane = t & 63;
  float w_seq[4], w_z0[4], w_z1[4], tmp[4];
  sm3d(sload(as_seq0 + 3), sload(as_seq0 + 4), sload(as_seq0 + 5), 1.f / 3.f, tmp);
  w_seq[0] = tmp[0]; w_seq[1] = tmp[1]; w_seq[2] = tmp[2]; w_seq[3] = 0.f;
  sm3d(sload(as_last_res0 + 3), sload(as_last_res0 + 4), sload(as_last_res0 + 5),
       1.f / 3.f, tmp);
  w_z0[0] = tmp[0]; w_z0[1] = tmp[1]; w_z0[2] = 0.f; w_z0[3] = tmp[2];
  sm2d(sload(as_last_seq1 + 0), sload(as_last_seq1 + 1), 0.5f, tmp);
  w_z1[0] = tmp[0]; w_z1[1] = tmp[1]; w_z1[2] = 0.f; w_z1[3] = 0.f;

  int nA[4], baseA[4];
  bool fits = true;
#pragma unroll
  for (int a = 0; a < 4; a++) {
    int key = a * NB + b;
    int base = key_base(off2, key);
    int ntot = key_end(off2, key) - base;
    int rs, re;
    if (ntot <= CAP) {
      int mid = __builtin_amdgcn_readfirstlane(rofftab[(size_t)key * RB + RBH]);
      rs = bh ? mid : 0;
      re = bh ? ntot : mid;
    } else {
      rs = 0; re = ntot; fits = false;
    }
    baseA[a] = base + rs;
    nA[a] = re - rs;
    if (nA[a] > CAPH) fits = false;
  }
  int rowbase = b * RB + bh * RBH + wv * 4;
  if (fits) {
#pragma unroll
    for (int a = 0; a < 4; a++) {
      int n = nA[a], base = baseA[a];
      for (int i = t; i < n; i += 256) {
        int2 p = epk[base + i];
        se[a * CAPH + i] = make_int2((p.x & 0x1FFFF) << 7, p.y);
      }
    }
    if (t < 4 * (RBH + 1)) {
      int a = t / (RBH + 1), rr = t % (RBH + 1);
      int key = a * NB + b;
      int kb = off2[(size_t)key << 6];
      int ke = (key + 1 < NKEY) ? off2[(size_t)(key + 1) << 6] : (int)ME;
      int rs0 = bh ? rofftab[(size_t)key * RB + RBH] : 0;
      int ar = bh * RBH + rr;
      int v = (ar < RB) ? rofftab[(size_t)key * RB + ar] : (ke - kb);
      ro[a][rr] = v - rs0;
    }
    __syncthreads();
    const unsigned char* sbs = (const unsigned char*)spb_s;
    const unsigned char* sbt = (const unsigned char*)spb_t;
    unsigned lane2 = (unsigned)lane << 1;
    // both planes (adjs 0,1)
    auto tl2 = [&](const int2* sp, int i, int e, float& s0, float& s1,
                   float& t0, float& t1) {
      for (; i + 3 < e; i += 4) {
        int2 p0 = sp[i], p1 = sp[i + 1], p2 = sp[i + 2], p3 = sp[i + 3];
        float gs0 = bf_s(*(const unsigned short*)(sbs + ((unsigned)p0.x + lane2)));
        float gt0 = bf_s(*(const unsigned short*)(sbt + ((unsigned)p0.x + lane2)));
        float gs1 = bf_s(*(const unsigned short*)(sbs + ((unsigned)p1.x + lane2)));
        float gt1 = bf_s(*(const unsigned short*)(sbt + ((unsigned)p1.x + lane2)));
        float gs2 = bf_s(*(const unsigned short*)(sbs + ((unsigned)p2.x + lane2)));
        float gt2 = bf_s(*(const unsigned short*)(sbt + ((unsigned)p2.x + lane2)));
        float gs3 = bf_s(*(const unsigned short*)(sbs + ((unsigned)p3.x + lane2)));
        float gt3 = bf_s(*(const unsigned short*)(sbt + ((unsigned)p3.x + lane2)));
        float v0 = __int_as_float(p0.y), v1 = __int_as_float(p1.y);
        float v2 = __int_as_float(p2.y), v3 = __int_as_float(p3.y);
        s0 = fmaf(v0, gs0, s0); t0 = fmaf(v0, gt0, t0);
        s1 = fmaf(v1, gs1, s1); t1 = fmaf(v1, gt1, t1);
        s0 = fmaf(v2, gs2, s0); t0 = fmaf(v2, gt2, t0);
        s1 = fmaf(v3, gs3, s1); t1 = fmaf(v3, gt3, t1);
      }
      for (; i < e; i++) {
        int2 p = sp[i];
        float gs = bf_s(*(const unsigned short*)(sbs + ((unsigned)p.x + lane2)));
        float gt = bf_s(*(const unsigned short*)(sbt + ((unsigned)p.x + lane2)));
        float v = __int_as_float(p.y);
        s0 = fmaf(v, gs, s0); t0 = fmaf(v, gt, t0);
      }
    };
    // s-plane only (adjs 2,3: t-weights are structurally zero — half the bytes)
    auto tl1 = [&](const int2* sp, int i, int e, float& s0, float& s1) {
      for (; i + 3 < e; i += 4) {
        int2 p0 = sp[i], p1 = sp[i + 1], p2 = sp[i + 2], p3 = sp[i + 3];
        float g0 = bf_s(*(const unsigned short*)(sbs + ((unsigned)p0.x + lane2)));
        float g1 = bf_s(*(const unsigned short*)(sbs + ((unsigned)p1.x + lane2)));
        float g2 = bf_s(*(const unsigned short*)(sbs + ((unsigned)p2.x + lane2)));
        float g3 = bf_s(*(const unsigned short*)(sbs + ((unsigned)p3.x + lane2)));
        s0 = fmaf(__int_as_float(p0.y), g0, s0);
        s1 = fmaf(__int_as_float(p1.y), g1, s1);
        s0 = fmaf(__int_as_float(p2.y), g2, s0);
        s1 = fmaf(__int_as_float(p3.y), g3, s1);
      }
      for (; i < e; i++) {
        int2 p = sp[i];
        float g = bf_s(*(const unsigned short*)(sbs + ((unsigned)p.x + lane2)));
        s0 = fmaf(__int_as_float(p.y), g, s0);
      }
    };
    for (int r8 = 0; r8 < 4; r8++) {
      int r = wv * 4 + r8;
      float vres = 0.f, vz0 = 0.f, vz1 = 0.f;
      {  // pair (0,1): both planes live
        const int2* spA = se;
        const int2* spB = se + CAPH;
        int iA = ro[0][r], eA = ro[0][r + 1];
        int iB = ro[1][r], eB = ro[1][r + 1];
        float sA0 = 0.f, sA1 = 0.f, tA0 = 0.f, tA1 = 0.f;
        float sB0 = 0.f, sB1 = 0.f, tB0 = 0.f, tB1 = 0.f;
        int dA = eA - iA, dB = eB - iB;
        int m = (dA < dB ? dA : dB) >> 2;
        for (int k = 0; k < m; k++) {
          int2 a0 = spA[iA], a1 = spA[iA + 1], a2 = spA[iA + 2], a3 = spA[iA + 3];
          int2 b0 = spB[iB], b1 = spB[iB + 1], b2 = spB[iB + 2], b3 = spB[iB + 3];
          float gsA0 = bf_s(*(const unsigned short*)(sbs + ((unsigned)a0.x + lane2)));
          float gtA0 = bf_s(*(const unsigned short*)(sbt + ((unsigned)a0.x + lane2)));
          float gsA1 = bf_s(*(const unsigned short*)(sbs + ((unsigned)a1.x + lane2)));
          float gtA1 = bf_s(*(const unsigned short*)(sbt + ((unsigned)a1.x + lane2)));
          float gsA2 = bf_s(*(const unsigned short*)(sbs + ((unsigned)a2.x + lane2)));
          float gtA2 = bf_s(*(const unsigned short*)(sbt + ((unsigned)a2.x + lane2)));
          float gsA3 = bf_s(*(const unsigned short*)(sbs + ((unsigned)a3.x + lane2)));
          float gtA3 = bf_s(*(const unsigned short*)(sbt + ((unsigned)a3.x + lane2)));
          float gsB0 = bf_s(*(const unsigned short*)(sbs + ((unsigned)b0.x + lane2)));
          float gtB0 = bf_s(*(const unsigned short*)(sbt + ((unsigned)b0.x + lane2)));
          float gsB1 = bf_s(*(const unsigned short*)(sbs + ((unsigned)b1.x + lane2)));
          float gtB1 = bf_s(*(const unsigned short*)(sbt + ((unsigned)b1.x + lane2)));
          float gsB2 = bf_s(*(const unsigned short*)(sbs + ((unsigned)b2.x + lane2)));
          float gtB2 = bf_s(*(const unsigned short*)(sbt + ((unsigned)b2.x + lane2)));
          float gsB3 = bf_s(*(const unsigned short*)(sbs + ((unsigned)b3.x + lane2)));
          float gtB3 = bf_s(*(const unsigned short*)(sbt + ((unsigned)b3.x + lane2)));
          float vA0 = __int_as_float(a0.y), vA1 = __int_as_float(a1.y);
          float vA2 = __int_as_float(a2.y), vA3 = __int_as_float(a3.y);
          float vB0 = __int_as_float(b0.y), vB1 = __int_as_float(b1.y);
          float vB2 = __int_as_float(b2.y), vB3 = __int_as_float(b3.y);
          sA0 = fmaf(vA0, gsA0, sA0); tA0 = fmaf(vA0, gtA0, tA0);
          sA1 = fmaf(vA1, gsA1, sA1); tA1 = fmaf(vA1, gtA1, tA1);
          sA0 = fmaf(vA2, gsA2, sA0); tA0 = fmaf(vA2, gtA2, tA0);
          sA1 = fmaf(vA3, gsA3, sA1); tA1 = fmaf(vA3, gtA3, tA1);
          sB0 = fmaf(vB0, gsB0, sB0); tB0 = fmaf(vB0, gtB0, tB0);
          sB1 = fmaf(vB1, gsB1, sB1); tB1 = fmaf(vB1, gtB1, tB1);
          sB0 = fmaf(vB2, gsB2, sB0); tB0 = fmaf(vB2, gtB2, tB0);
          sB1 = fmaf(vB3, gsB3, sB1); tB1 = fmaf(vB3, gtB3, tB1);
          iA += 4; iB += 4;
        }
        tl2(spA, iA, eA, sA0, sA1, tA0, tA1);
        tl2(spB, iB, eB, sB0, sB1, tB0, tB1);
        float sA = sA0 + sA1, tA = tA0 + tA1;
        float sB = sB0 + sB1, tB = tB0 + tB1;
        vres = fmaf(w_seq[0], sA, fmaf(w_seq[1], sB, vres));
        vz0  = fmaf(w_z0[0], sA, fmaf(w_z0[1], sB, vz0));
        vz1  = fmaf(w_z1[0], tA, fmaf(w_z1[1], tB, vz1));
      }
      {  // pair (2,3): s-plane only
        const int2* spA = se + 2 * CAPH;
        const int2* spB = se + 3 * CAPH;
        int iA = ro[2][r], eA = ro[2][r + 1];
        int iB = ro[3][r], eB = ro[3][r + 1];
        float sA0 = 0.f, sA1 = 0.f, sB0 = 0.f, sB1 = 0.f;
        int dA = eA - iA, dB = eB - iB;
        int m = (dA < dB ? dA : dB) >> 2;
        for (int k = 0; k < m; k++) {
          int2 a0 = spA[iA], a1 = spA[iA + 1], a2 = spA[iA + 2], a3 = spA[iA + 3];
          int2 b0 = spB[iB], b1 = spB[iB + 1], b2 = spB[iB + 2], b3 = spB[iB + 3];
          float gA0 = bf_s(*(const unsigned short*)(sbs + ((unsigned)a0.x + lane2)));
          float gA1 = bf_s(*(const unsigned short*)(sbs + ((unsigned)a1.x + lane2)));
          float gA2 = bf_s(*(const unsigned short*)(sbs + ((unsigned)a2.x + lane2)));
          float gA3 = bf_s(*(const unsigned short*)(sbs + ((unsigned)a3.x + lane2)));
          float gB0 = bf_s(*(const unsigned short*)(sbs + ((unsigned)b0.x + lane2)));
          float gB1 = bf_s(*(const unsigned short*)(sbs + ((unsigned)b1.x + lane2)));
          float gB2 = bf_s(*(const unsigned short*)(sbs + ((unsigned)b2.x + lane2)));
          float gB3 = bf_s(*(const unsigned short*)(sbs + ((unsigned)b3.x + lane2)));
          sA0 = fmaf(__int_as_float(a0.y), gA0, sA0);
          sA1 = fmaf(__int_as_float(a1.y), gA1, sA1);
          sA0 = fmaf(__int_as_float(a2.y), gA2, sA0);
          sA1 = fmaf(__int_as_float(a3.y), gA3, sA1);
          sB0 = fmaf(__int_as_float(b0.y), gB0, sB0);
          sB1 = fmaf(__int_as_float(b1.y), gB1, sB1);
          sB0 = fmaf(__int_as_float(b2.y), gB2, sB0);
          sB1 = fmaf(__int_as_float(b3.y), gB3, sB1);
          iA += 4; iB += 4;
        }
        tl1(spA, iA, eA, sA0, sA1);
        tl1(spB, iB, eB, sB0, sB1);
        float sA = sA0 + sA1, sB = sB0 + sB1;
        vres = fmaf(w_seq[2], sA, fmaf(w_seq[3], sB, vres));
        vz0  = fmaf(w_z0[2], sA, fmaf(w_z0[3], sB, vz0));
      }
      size_t o = (size_t)(rowbase + r8) * 64 + lane;
      float s2v = cres[o] + vres;   // cres is dead after this kernel: no store-back
      s2b[o] = bf1(s2v);
      cz0[o] += vz0;
      cz1[o] += vz1;
    }
  } else {
    float dres[4], dz0[4], dz1[4];
#pragma unroll
    for (int r = 0; r < 4; r++) { dres[r] = 0.f; dz0[r] = 0.f; dz1[r] = 0.f; }
    for (int a = 0; a < 4; a++) {
      int base = baseA[a], n = nA[a];
      for (int i = 0; i < n; i++) {
        int2 p = epk[base + i];
        int lr = p.x >> 17, c = p.x & 0x1FFFF;
        float v = __int_as_float(p.y);
        float gs = v * bf_s(spb_s[(size_t)c * 64 + lane]);
        float gt = v * bf_s(spb_t[(size_t)c * 64 + lane]);
#pragma unroll
        for (int r8 = 0; r8 < 4; r8++) {
          if (lr == bh * RBH + wv * 4 + r8) {
            dres[r8] = fmaf(w_seq[a], gs, dres[r8]);
            dz0[r8]  = fmaf(w_z0[a], gs, dz0[r8]);
            dz1[r8]  = fmaf(w_z1[a], gt, dz1[r8]);
          }
        }
      }
    }
#pragma unroll
    for (int r8 = 0; r8 < 4; r8++) {
      size_t o = (size_t)(rowbase + r8) * 64 + lane;
      float s2v = cres[o] + dres[r8];
      s2b[o] = bf1(s2v);
      cz0[o] += dz0[r8];
      cz1[o] += dz1[r8];
    }
  }
}

// stage 3 + final fused: gather s2b (adjs 0,1), z0 = cz0 + dz kept in registers;
// epilogue de-shuffled with NAMED SCALAR accumulators (no register arrays across
// non-unrolled loops — avoids the scratch-spill cliff seen in R7).
__global__ __launch_bounds__(256, 8) void st3f_kernel(
    const int* __restrict__ off2,
    const int* __restrict__ rofftab, const int2* __restrict__ epk,
    const unsigned short* __restrict__ s2b, const float* __restrict__ as_last_seq0,
    const float* __restrict__ cz0, const float* __restrict__ cz1,
    const float* __restrict__ attn1_W, const float* __restrict__ attn1_b,
    const float* __restrict__ attn2_W, const float* __restrict__ attn2_b,
    const float* __restrict__ cls_W, const float* __restrict__ cls_b,
    float* __restrict__ out) {
  __shared__ int2 se[2 * CAPH];   // gather: (byte off, val); epilogue: reused as g-store
  __shared__ int ro[2][RBH + 1];
  __shared__ float2 psh[4][4];    // per wave, per row: {p0, p1}
  int bb = blockIdx.x;
  int b = bb >> 1, bh = bb & 1;
  int t = threadIdx.x, wv = t >> 6, lane = t & 63;
  float wA[2];
  sm2d(sload(as_last_seq0 + 0), sload(as_last_seq0 + 1), 0.5f, wA);
  float wA0 = wA[0], wA1 = wA[1];
  int nA[2], baseA[2];
  bool fits = true;   // block-uniform (derived via readfirstlane)
#pragma unroll
  for (int a = 0; a < 2; a++) {
    int key = a * NB + b;
    int base = key_base(off2, key);
    int ntot = key_end(off2, key) - base;
    int rs, re;
    if (ntot <= CAP) {
      int mid = __builtin_amdgcn_readfirstlane(rofftab[(size_t)key * RB + RBH]);
      rs = bh ? mid : 0;
      re = bh ? ntot : mid;
    } else {
      rs = 0; re = ntot; fits = false;
    }
    baseA[a] = base + rs;
    nA[a] = re - rs;
    if (nA[a] > CAPH) fits = false;
  }
  int rowbase = b * RB + bh * RBH + wv * 4;
  float dz0r = 0.f, dz1r = 0.f, dz2r = 0.f, dz3r = 0.f;
  if (fits) {
#pragma unroll
    for (int a = 0; a < 2; a++) {
      int n = nA[a], base = baseA[a];
      for (int i = t; i < n; i += 256) {
        int2 p = epk[base + i];
        se[a * CAPH + i] = make_int2((p.x & 0x1FFFF) << 7, p.y);
      }
    }
    if (t < 2 * (RBH + 1)) {
      int a = t / (RBH + 1), rr = t % (RBH + 1);
      int key = a * NB + b;
      int kb = off2[(size_t)key << 6];
      int ke = (key + 1 < NKEY) ? off2[(size_t)(key + 1) << 6] : (int)ME;
      int rs0 = bh ? rofftab[(size_t)key * RB + RBH] : 0;
      int ar = bh * RBH + rr;
      int v = (ar < RB) ? rofftab[(size_t)key * RB + ar] : (ke - kb);
      ro[a][rr] = v - rs0;
    }
    __syncthreads();
    const unsigned char* sb = (const unsigned char*)s2b;
    unsigned lane2 = (unsigned)lane << 1;
    auto tlu = [&](const int2* sp, int i, int e, float& s0, float& s1) {
      for (; i + 3 < e; i += 4) {
        int2 p0 = sp[i], p1 = sp[i + 1], p2 = sp[i + 2], p3 = sp[i + 3];
        float g0 = bf_s(*(const unsigned short*)(sb + ((unsigned)p0.x + lane2)));
        float g1 = bf_s(*(const unsigned short*)(sb + ((unsigned)p1.x + lane2)));
        float g2 = bf_s(*(const unsigned short*)(sb + ((unsigned)p2.x + lane2)));
        float g3 = bf_s(*(const unsigned short*)(sb + ((unsigned)p3.x + lane2)));
        s0 = fmaf(__int_as_float(p0.y), g0, s0);
        s1 = fmaf(__int_as_float(p1.y), g1, s1);
        s0 = fmaf(__int_as_float(p2.y), g2, s0);
        s1 = fmaf(__int_as_float(p3.y), g3, s1);
      }
      for (; i < e; i++) {
        int2 p = sp[i];
        float g = bf_s(*(const unsigned short*)(sb + ((unsigned)p.x + lane2)));
        s0 = fmaf(__int_as_float(p.y), g, s0);
      }
    };
    auto row_gather = [&](int r) -> float {
      const int2* spA = se;
      const int2* spB = se + CAPH;
      int iA = ro[0][r], eA = ro[0][r + 1];
      int iB = ro[1][r], eB = ro[1][r + 1];
      float sA0 = 0.f, sA1 = 0.f, sB0 = 0.f, sB1 = 0.f;
      int dA = eA - iA, dB = eB - iB;
      int m = (dA < dB ? dA : dB) >> 2;
      for (int k = 0; k < m; k++) {
        int2 a0 = spA[iA], a1 = spA[iA + 1], a2 = spA[iA + 2], a3 = spA[iA + 3];
        int2 b0 = spB[iB], b1 = spB[iB + 1], b2 = spB[iB + 2], b3 = spB[iB + 3];
        float gA0 = bf_s(*(const unsigned short*)(sb + ((unsigned)a0.x + lane2)));
        float gA1 = bf_s(*(const unsigned short*)(sb + ((unsigned)a1.x + lane2)));
        float gA2 = bf_s(*(const unsigned short*)(sb + ((unsigned)a2.x + lane2)));
        float gA3 = bf_s(*(const unsigned short*)(sb + ((unsigned)a3.x + lane2)));
        float gB0 = bf_s(*(const unsigned short*)(sb + ((unsigned)b0.x + lane2)));
        float gB1 = bf_s(*(const unsigned short*)(sb + ((unsigned)b1.x + lane2)));
        float gB2 = bf_s(*(const unsigned short*)(sb + ((unsigned)b2.x + lane2)));
        float gB3 = bf_s(*(const unsigned short*)(sb + ((unsigned)b3.x + lane2)));
        sA0 = fmaf(__int_as_float(a0.y), gA0, sA0);
        sA1 = fmaf(__int_as_float(a1.y), gA1, sA1);
        sA0 = fmaf(__int_as_float(a2.y), gA2, sA0);
        sA1 = fmaf(__int_as_float(a3.y), gA3, sA1);
        sB0 = fmaf(__int_as_float(b0.y), gB0, sB0);
        sB1 = fmaf(__int_as_float(b1.y), gB1, sB1);
        sB0 = fmaf(__int_as_float(b2.y), gB2, sB0);
        sB1 = fmaf(__int_as_float(b3.y), gB3, sB1);
        iA += 4; iB += 4;
      }
      tlu(spA, iA, eA, sA0, sA1);
      tlu(spB, iB, eB, sB0, sB1);
      return fmaf(wA0, sA0 + sA1, wA1 * (sB0 + sB1));
    };
    dz0r = row_gather(wv * 4 + 0);
    dz1r = row_gather(wv * 4 + 1);
    dz2r = row_gather(wv * 4 + 2);
    dz3r = row_gather(wv * 4 + 3);
  } else {
    for (int a = 0; a < 2; a++) {
      int base = baseA[a], n = nA[a];
      float wa = a ? wA1 : wA0;
      for (int i = 0; i < n; i++) {
        int2 p = epk[base + i];
        int lr = p.x >> 17, c = p.x & 0x1FFFF;
        float v = __int_as_float(p.y);
        float gs = v * bf_s(s2b[(size_t)c * 64 + lane]);
        int lr0 = bh * RBH + wv * 4;
        if (lr == lr0 + 0) dz0r = fmaf(wa, gs, dz0r);
        if (lr == lr0 + 1) dz1r = fmaf(wa, gs, dz1r);
        if (lr == lr0 + 2) dz2r = fmaf(wa, gs, dz2r);
        if (lr == lr0 + 3) dz3r = fmaf(wa, gs, dz3r);
      }
    }
  }

  // ---- fused epilogue (de-shuffled, scalar-only): reuse se as g-store ----
  __syncthreads();
  float2* gsh = (float2*)se;            // [4 waves][4 rows][64] float2 {g0,g1} = 8 KB
  float aw = attn2_W[lane];
  float ab = attn1_b[lane];
  float a2b = sload(attn2_b);

  // phase A: LN + gelu per row; stash {g0,g1} (1 ds_write_b64/row)
  auto ln_gelu_store = [&](float dzr, int r8) {
    size_t o = (size_t)(rowbase + r8) * 64 + lane;
    float z0 = cz0[o] + dzr;
    float z1 = cz1[o];
    float m0 = wave_bsum(z0) * (1.f / 64.f);
    float dv0 = z0 - m0;
    float var0 = wave_bsum(dv0 * dv0) * (1.f / 64.f);
    float y0 = dv0 * rsqrtf(var0 + 1e-5f);
    float g0 = 0.5f * y0 * (1.f + erff(y0 * 0.70710678118654752f));
    float m1 = wave_bsum(z1) * (1.f / 64.f);
    float dv1 = z1 - m1;
    float var1 = wave_bsum(dv1 * dv1) * (1.f / 64.f);
    float y1 = dv1 * rsqrtf(var1 + 1e-5f);
    float g1 = 0.5f * y1 * (1.f + erff(y1 * 0.70710678118654752f));
    gsh[((size_t)wv * 4 + r8) * 64 + lane] = make_float2(g0, g1);
  };
  ln_gelu_store(dz0r, 0);
  ln_gelu_store(dz1r, 1);
  ln_gelu_store(dz2r, 2);
  ln_gelu_store(dz3r, 3);

  // phase B: joint 4-row attn1 matvec via uniform-address b128 broadcast reads.
  // Named scalar accumulators only (no arrays -> no scratch). j-order matches
  // the reference shfl loop -> t accumulation bit-exact.
  float t00 = ab, t01 = ab, t02 = ab, t03 = ab;
  float u10 = ab, u11 = ab, u12 = ab, u13 = ab;
  const float4* gq = (const float4*)(gsh + (size_t)wv * 256);  // 32 float4 per row
  for (int j2 = 0; j2 < 32; j2++) {
    float w0 = attn1_W[(2 * j2) * HD + lane];
    float w1 = attn1_W[(2 * j2 + 1) * HD + lane];
    float4 ga = gq[j2];          // row 0: {g0_j, g1_j, g0_j+1, g1_j+1}
    float4 gb = gq[32 + j2];     // row 1
    float4 gc = gq[64 + j2];     // row 2
    float4 gd = gq[96 + j2];     // row 3
    t00 = fmaf(ga.x, w0, t00); u10 = fmaf(ga.y, w0, u10);
    t00 = fmaf(ga.z, w1, t00); u10 = fmaf(ga.w, w1, u10);
    t01 = fmaf(gb.x, w0, t01); u11 = fmaf(gb.y, w0, u11);
    t01 = fmaf(gb.z, w1, t01); u11 = fmaf(gb.w, w1, u11);
    t02 = fmaf(gc.x, w0, t02); u12 = fmaf(gc.y, w0, u12);
    t02 = fmaf(gc.z, w1, t02); u12 = fmaf(gc.w, w1, u12);
    t03 = fmaf(gd.x, w0, t03); u13 = fmaf(gd.y, w0, u13);
    t03 = fmaf(gd.z, w1, t03); u13 = fmaf(gd.w, w1, u13);
  }

  // phase C: per-row attention scores + softmax; stash {p0,p1} (constant row idx)
  auto scorer = [&](float tv0, float tv1, int r) {
    float tt0 = tanhf(tv0), tt1 = tanhf(tv1);
    float a0 = wave_bsum(tt0 * aw) + a2b;
    float a1 = wave_bsum(tt1 * aw) + a2b;
    float mx = fmaxf(a0, a1);
    float e0 = expf(a0 - mx), e1 = expf(a1 - mx);
    float inv = 1.f / (e0 + e1);
    if (lane == 0) psh[wv][r] = make_float2(e0 * inv, e1 * inv);
  };
  scorer(t00, u10, 0);
  scorer(t01, u11, 1);
  scorer(t02, u12, 2);
  scorer(t03, u13, 3);

  // phase D: classifier. out = p0*(g0@C) + p1*(g1@C) + b.
  // lanes 0..31: (row, class) = (lane>>3, lane&7); coalesced 128B store.
  if (lane < 32) {
    int r = lane >> 3, k = lane & 7;
    float2 pp = psh[wv][r];
    const float4* gr = (const float4*)(gsh + ((size_t)wv * 4 + r) * 64);
    float u0 = 0.f, u1 = 0.f;
    for (int j2 = 0; j2 < 32; j2++) {
      float4 gg = gr[j2];                 // {g0_j, g1_j, g0_j+1, g1_j+1}
      int j = j2 * 2;
      float c0 = cls_W[j * 8 + k];
      float c1 = cls_W[(j + 1) * 8 + k];
      u0 = fmaf(gg.x, c0, u0); u1 = fmaf(gg.y, c0, u1);
      u0 = fmaf(gg.z, c1, u0); u1 = fmaf(gg.w, c1, u1);
    }
    int n = rowbase + r;
    out[(size_t)n * 8 + k] = fmaf(pp.x, u0, pp.y * u1) + cls_b[k];
  }
}

extern "C" void kernel_launch(void* const* d_in, const int* in_sizes, int n_in,
                              void* d_out, int out_size, void* d_ws, size_t ws_size,
                              hipStream_t stream) {
  const float* node_feats   = (const float*)d_in[0];
  const int*   node_types   = (const int*)d_in[1];
  const int*   adj_rows     = (const int*)d_in[2];
  const int*   adj_cols     = (const int*)d_in[3];
  const float* adj_vals     = (const float*)d_in[4];
  const float* type_W       = (const float*)d_in[5];
  const float* type_b       = (const float*)d_in[6];
  const float* aW0          = (const float*)d_in[7];
  const float* ab0          = (const float*)d_in[8];
  const float* aW1          = (const float*)d_in[9];
  const float* ab1          = (const float*)d_in[10];
  const float* as_seq0      = (const float*)d_in[11];
  const float* as_last_seq0 = (const float*)d_in[12];
  const float* as_res0      = (const float*)d_in[13];
  const float* as_last_res0 = (const float*)d_in[14];
  const float* as_seq1      = (const float*)d_in[15];
  const float* as_last_seq1 = (const float*)d_in[16];
  const float* as_last_res1 = (const float*)d_in[17];
  const float* attn1_W      = (const float*)d_in[18];
  const float* attn1_b      = (const float*)d_in[19];
  const float* attn2_W      = (const float*)d_in[20];
  const float* attn2_b      = (const float*)d_in[21];
  const float* cls_W        = (const float*)d_in[22];
  const float* cls_b        = (const float*)d_in[23];
  float* out = (float*)d_out;
  float* ws = (float*)d_ws;

  unsigned int*   xpb   = (unsigned int*)(ws + XPB_OFF);
  unsigned short* spb_s = (unsigned short*)(ws + SPB_OFF);
  unsigned short* spb_t = (unsigned short*)(ws + SPB_OFF + NP / 2);
  float*          cres  = ws + CRES_OFF;
  float*          cz0   = ws + CZ0_OFF;
  float*          cz1   = ws + CZ1_OFF;
  unsigned short* s2b   = (unsigned short*)(ws + S2B_OFF);
  int2*           epk   = (int2*)(ws + EPK_OFF);
  int*            cnt2  = (int*)(ws + CNT2_OFF);
  int*            off2  = (int*)(ws + OFF2_OFF);
  int*            part  = (int*)(ws + PART_OFF);
  int*            roff  = (int*)(ws + ROFF_OFF);
  int*            ncnt  = (int*)(ws + NCNT_OFF);
  int*            noff  = (int*)(ws + NOFF_OFF);
  int*            nperm = (int*)(ws + NPERM_OFF);

  // node type sort + typed projection (8 same-type nodes per wave)
  nhist_kernel<<<NCH, 256, 0, stream>>>(node_types, ncnt);
  nscan_kernel<<<1, 256, 0, stream>>>(ncnt, noff);
  nscatter_kernel<<<NCH, 256, 0, stream>>>(node_types, noff, nperm);
  hid2_kernel<<<NNODES / 32, 256, 0, stream>>>(node_feats, node_types, nperm,
                                               type_W, type_b, aW0, ab0, aW1, ab1, xpb);

  // deterministic edge build: hist2 -> scan -> LDS-cursor scatter -> pack+sort
  // (histb2/scatterd at 1024 threads: 16 waves/CU for the latency-bound phases)
  histb2_kernel<<<dim3(CHK, 4), 1024, 0, stream>>>(adj_rows, cnt2);
  scan1_kernel<<<SCAN1B, 256, 0, stream>>>(cnt2, off2, part);
  scan2_kernel<<<1, 1024, 0, stream>>>(part);
  scan3_kernel<<<SCAN1B, 256, 0, stream>>>(off2, part);
  scatterd_kernel<<<dim3(CHK, 4), 1024, 0, stream>>>(adj_rows, adj_cols, adj_vals, off2, epk);
  pack_kernel<<<NKEY, 256, 0, stream>>>(off2, epk, roff);

  // SpMM stages (arch-weight softmaxes computed inline; keyoff inlined from off2)
  st1_kernel<<<NB * 2, 256, 0, stream>>>(off2, roff, epk, xpb,
                                         as_seq0, as_res0, as_last_res0, as_seq1,
                                         as_last_res1,
                                         spb_s, spb_t, cres, cz0, cz1);
  st2_kernel<<<NB * 2, 256, 0, stream>>>(off2, roff, epk, spb_s, spb_t,
                                         as_seq0, as_last_res0, as_last_seq1,
                                         cres, s2b, cz0, cz1);
  // stage 3 + final fused (scalar-only de-shuffled epilogue; writes logits directly)
  st3f_kernel<<<NB * 2, 256, 0, stream>>>(off2, roff, epk, s2b, as_last_seq0,
                                          cz0, cz1,
                                          attn1_W, attn1_b, attn2_W, attn2_b,
                                          cls_W, cls_b, out);
}